// Round 5
// baseline (825.695 us; speedup 1.0000x reference)
//
#include <hip/hip_runtime.h>
#include <math.h>

#define BSZ   4
#define SEQL  2048
#define DIN   40
#define DM    128
#define DI    256
#define DS    16
#define NL    4
#define NHEAD 4
#define DHEAD 32
#define KLM   100
#define NC    128       // chunks per sequence
#define TC    16        // SEQL / NC
#define PROWS 16        // rows per pre block
#define EROWS 16

__device__ __forceinline__ float sigmoidf_(float x){ return 1.0f/(1.0f + expf(-x)); }
__device__ __forceinline__ float siluf_(float x){ return x/(1.0f + expf(-x)); }
__device__ __forceinline__ float softplusf_(float x){ return fmaxf(x,0.0f) + log1pf(expf(-fabsf(x))); }

__device__ __forceinline__ float block_sum256(float v, float* red){
  #pragma unroll
  for (int o=32;o>0;o>>=1) v += __shfl_down(v,o,64);
  __syncthreads();
  if ((threadIdx.x & 63)==0) red[threadIdx.x>>6] = v;
  __syncthreads();
  return red[0]+red[1]+red[2]+red[3];
}
__device__ __forceinline__ void load8(const float* p, float* r){
  const float4* q = (const float4*)p;
  float4 a=q[0], b=q[1];
  r[0]=a.x;r[1]=a.y;r[2]=a.z;r[3]=a.w; r[4]=b.x;r[5]=b.y;r[6]=b.z;r[7]=b.w;
}
__device__ __forceinline__ void store8(float* p, const float* r){
  float4* q = (float4*)p;
  q[0]=make_float4(r[0],r[1],r[2],r[3]);  q[1]=make_float4(r[4],r[5],r[6],r[7]);
}
__device__ __forceinline__ void load16(const float* p, float* r){
  load8(p, r); load8(p+8, r+8);
}

// ---------------- embed: 16 rows/block, weights amortized ----------------
__global__ __launch_bounds__(256) void embed_kernel(
    const float* __restrict__ x, const float* __restrict__ hw,
    const float* __restrict__ eW, const float* __restrict__ eb,
    const float* __restrict__ sW, const float* __restrict__ sb,
    float* __restrict__ hb, float* __restrict__ sk)
{
  __shared__ float xr[EROWS][DIN];
  const int t = threadIdx.x;
  const size_t R0 = (size_t)blockIdx.x * EROWS;
  for (int e=t; e<EROWS*DIN; e+=256) ((float*)xr)[e] = x[R0*DIN + e];
  __syncthreads();
  const int c = t & (DM-1), g = t >> 7;
  float ae[8], as[8];
  #pragma unroll
  for (int j=0;j<8;j++){ ae[j]=0.0f; as[j]=0.0f; }
  for (int k=0;k<DIN;k++){
    const float we  = eW[(size_t)k*DM + c];
    const float ws_ = sW[(size_t)k*DM + c];
    #pragma unroll
    for (int j=0;j<8;j++){
      const float xv = xr[g*8+j][k];
      ae[j] = fmaf(xv, we, ae[j]);
      as[j] = fmaf(xv, ws_, as[j]);
    }
  }
  const float ebv = eb[c], sbv = sb[c];
  #pragma unroll
  for (int j=0;j<8;j++){
    const size_t R = R0 + g*8 + j;
    const float w = hw[R];
    hb[R*DM + c] = (ae[j]+ebv)*w;
    sk[R*DM + c] = (as[j]+sbv)*w;
  }
}

// ---------------- LN + in_proj + silu: block = 16 rows x 128 cols; 2048 blocks ----------------
__global__ __launch_bounds__(256) void ln_inproj_kernel(
    const float* __restrict__ hb, const float* __restrict__ Wi,
    const float* __restrict__ lnw, const float* __restrict__ lnb,
    float* __restrict__ xpb, float* __restrict__ zsb)
{
  __shared__ float xin[PROWS][DM+4];
  const int t = threadIdx.x;
  const int rb = blockIdx.x >> 2, cc = blockIdx.x & 3;
  const size_t R0 = (size_t)rb * PROWS;
  const int colbase = cc * 128;

  { // LayerNorm: 16 threads per row, 8 floats each
    const int r = t >> 4, j = t & 15;
    const float* hr = hb + (R0 + r)*DM + j*8;
    const float4 v0 = *(const float4*)hr;
    const float4 v1 = *(const float4*)(hr+4);
    float s = v0.x+v0.y+v0.z+v0.w + v1.x+v1.y+v1.z+v1.w;
    #pragma unroll
    for (int o=8;o>0;o>>=1) s += __shfl_xor(s,o,16);
    const float m = s*(1.0f/DM);
    const float d0=v0.x-m,d1=v0.y-m,d2=v0.z-m,d3=v0.w-m;
    const float d4=v1.x-m,d5=v1.y-m,d6=v1.z-m,d7=v1.w-m;
    float ss = d0*d0+d1*d1+d2*d2+d3*d3+d4*d4+d5*d5+d6*d6+d7*d7;
    #pragma unroll
    for (int o=8;o>0;o>>=1) ss += __shfl_xor(ss,o,16);
    const float inv = 1.0f/sqrtf(ss*(1.0f/DM) + 1e-5f);
    const int c = j*8;
    xin[r][c+0]=d0*inv*lnw[c+0]+lnb[c+0]; xin[r][c+1]=d1*inv*lnw[c+1]+lnb[c+1];
    xin[r][c+2]=d2*inv*lnw[c+2]+lnb[c+2]; xin[r][c+3]=d3*inv*lnw[c+3]+lnb[c+3];
    xin[r][c+4]=d4*inv*lnw[c+4]+lnb[c+4]; xin[r][c+5]=d5*inv*lnw[c+5]+lnb[c+5];
    xin[r][c+6]=d6*inv*lnw[c+6]+lnb[c+6]; xin[r][c+7]=d7*inv*lnw[c+7]+lnb[c+7];
  }
  __syncthreads();

  const int r  = t >> 4;
  const int c8 = (t & 15) * 8;
  const float* Wc = Wi + colbase + c8;
  float a0=0,a1=0,a2=0,a3=0,a4=0,a5=0,a6=0,a7=0;
  for (int k=0;k<DM;k+=4){
    const float4 xv = *(const float4*)&xin[r][k];
    const float xx[4] = {xv.x, xv.y, xv.z, xv.w};
    #pragma unroll
    for (int j=0;j<4;j++){
      const float4 wa = *(const float4*)&Wc[(size_t)(k+j)*(2*DI)];
      const float4 wb = *(const float4*)&Wc[(size_t)(k+j)*(2*DI) + 4];
      a0=fmaf(xx[j],wa.x,a0); a1=fmaf(xx[j],wa.y,a1);
      a2=fmaf(xx[j],wa.z,a2); a3=fmaf(xx[j],wa.w,a3);
      a4=fmaf(xx[j],wb.x,a4); a5=fmaf(xx[j],wb.y,a5);
      a6=fmaf(xx[j],wb.z,a6); a7=fmaf(xx[j],wb.w,a7);
    }
  }
  const float4 s0 = make_float4(siluf_(a0),siluf_(a1),siluf_(a2),siluf_(a3));
  const float4 s1 = make_float4(siluf_(a4),siluf_(a5),siluf_(a6),siluf_(a7));
  const int col = colbase + c8;
  if (col < DI){
    float4* dst = (float4*)&xpb[(R0+r)*DI + col];
    dst[0] = s0; dst[1] = s1;
  } else {
    float4* dst = (float4*)&zsb[(R0+r)*DI + (col-DI)];
    dst[0] = s0; dst[1] = s1;
  }
}

// ---------------- x_proj + B/C rms + dt + lam + mean-dt; 512 blocks ----------------
__global__ __launch_bounds__(256) void xproj_kernel(
    const float* __restrict__ xpb, const float* __restrict__ Wx,
    const float* __restrict__ Wdt, const float* __restrict__ bdt,
    const float* __restrict__ Bb, const float* __restrict__ Cb,
    const float* __restrict__ Bnw, const float* __restrict__ Cnw,
    float* __restrict__ dtb, float* __restrict__ Bmb, float* __restrict__ Cmb,
    float* __restrict__ lamb, float* __restrict__ mdtb)
{
  __shared__ float xps[PROWS][DI+4];
  __shared__ float spl[PROWS][40];
  __shared__ float pr[PROWS][4];
  const int t = threadIdx.x;
  const size_t R0 = (size_t)blockIdx.x * PROWS;

  for (int e=t; e<PROWS*64; e+=256){
    const int r = e >> 6, q = e & 63;
    *(float4*)&xps[r][q*4] = *(const float4*)&xpb[(R0+r)*DI + q*4];
  }
  __syncthreads();

  // sp = xp @ Wx. 272 tasks = 16 rows x 17 col-pairs
  for (int e=t; e<272; e+=256){
    const int r = e & 15, op = e >> 4;
    float ax=0.0f, ay=0.0f;
    for (int k=0;k<DI;k+=4){
      const float4 xv = *(const float4*)&xps[r][k];
      const float2 w0 = *(const float2*)&Wx[(size_t)(k+0)*34 + 2*op];
      const float2 w1 = *(const float2*)&Wx[(size_t)(k+1)*34 + 2*op];
      const float2 w2 = *(const float2*)&Wx[(size_t)(k+2)*34 + 2*op];
      const float2 w3 = *(const float2*)&Wx[(size_t)(k+3)*34 + 2*op];
      ax = fmaf(xv.x,w0.x,ax); ay = fmaf(xv.x,w0.y,ay);
      ax = fmaf(xv.y,w1.x,ax); ay = fmaf(xv.y,w1.y,ay);
      ax = fmaf(xv.z,w2.x,ax); ay = fmaf(xv.z,w2.y,ay);
      ax = fmaf(xv.w,w3.x,ax); ay = fmaf(xv.w,w3.y,ay);
    }
    spl[r][2*op] = ax; spl[r][2*op+1] = ay;
  }
  __syncthreads();

  { // B/C rms-norm: thread (r, s) does both B and C
    const int r = t >> 4, s = t & 15;
    const float vB = spl[r][s] + Bb[s];
    float ssB = vB*vB;
    #pragma unroll
    for (int o=8;o>0;o>>=1) ssB += __shfl_xor(ssB,o,16);
    Bmb[(R0+r)*DS + s] = vB * (1.0f/sqrtf(ssB*(1.0f/DS) + 1.1920929e-07f)) * Bnw[s];
    const float vC = spl[r][DS+s] + Cb[s];
    float ssC = vC*vC;
    #pragma unroll
    for (int o=8;o>0;o>>=1) ssC += __shfl_xor(ssC,o,16);
    Cmb[(R0+r)*DS + s] = vC * (1.0f/sqrtf(ssC*(1.0f/DS) + 1.1920929e-07f)) * Cnw[s];
  }

  { // dt
    const int lane = t & 63, w = t >> 6;
    const float wdt = Wdt[t], bdtv = bdt[t];
    #pragma unroll 4
    for (int r=0;r<PROWS;r++){
      const float dval = softplusf_(fmaf(spl[r][32], wdt, bdtv));
      dtb[(R0+r)*DI + t] = dval;
      float s = dval;
      #pragma unroll
      for (int o=32;o>0;o>>=1) s += __shfl_xor(s,o,64);
      if (lane==0) pr[r][w] = s;
    }
    if (t < PROWS) lamb[R0+t] = sigmoidf_(spl[t][33]);
  }
  __syncthreads();
  if (t < PROWS)
    mdtb[R0+t] = (pr[t][0]+pr[t][1]+pr[t][2]+pr[t][3])*(1.0f/DI);
}

// ---------------- cumsum (f64) + cos/sin table ----------------
__global__ __launch_bounds__(256) void cumsum_cs_kernel(
    const float* __restrict__ mdt, const float* __restrict__ rf,
    float2* __restrict__ cst)
{
  __shared__ double csum[SEQL];   // 16 KB
  __shared__ double wsum[4];
  __shared__ double fqs[8];
  const int b = blockIdx.x, t = threadIdx.x;
  const int lane = t & 63, w = t >> 6;
  if (t < 8){
    const double xfr = (double)rf[t];
    fqs[t] = fmax(xfr, 0.0) + log1p(exp(-fabs(xfr)));
  }
  const float* p = mdt + (size_t)b*SEQL + (size_t)t*8;
  double v[8]; double s = 0.0;
  #pragma unroll
  for (int q=0;q<8;q++){ v[q] = (double)p[q]; s += v[q]; }
  double sc = s;
  #pragma unroll
  for (int o=1;o<64;o<<=1){
    const double nb = __shfl_up(sc, o, 64);
    if (lane >= o) sc += nb;
  }
  if (lane==63) wsum[w] = sc;
  __syncthreads();
  double woff = 0.0;
  for (int j=0;j<w;j++) woff += wsum[j];
  double run = woff + sc - s;
  #pragma unroll
  for (int q=0;q<8;q++){ run += v[q]; csum[t*8+q] = run; }
  __syncthreads();

  const double TWO_PI = 6.283185307179586;
  const double INV2PI = 0.15915494309189535;
  for (int j=0;j<8;j++){
    const int rloc = j*256 + t;
    const double ab = csum[rloc];
    float2 o8[8];
    #pragma unroll
    for (int f=0; f<8; f++){
      const double ang = ab * fqs[f];
      const double red = ang - floor(ang*INV2PI)*TWO_PI;
      float sa, ca;
      __sincosf((float)red, &sa, &ca);
      o8[f] = make_float2(ca, sa);
    }
    float4* dst = (float4*)&cst[((size_t)b*SEQL + rloc)*8];
    dst[0] = make_float4(o8[0].x,o8[0].y,o8[1].x,o8[1].y);
    dst[1] = make_float4(o8[2].x,o8[2].y,o8[3].x,o8[3].y);
    dst[2] = make_float4(o8[4].x,o8[4].y,o8[5].x,o8[5].y);
    dst[3] = make_float4(o8[6].x,o8[6].y,o8[7].x,o8[7].y);
  }
}

// ---------------- scan phase 1 (s-split, 512 threads) ----------------
__global__ __launch_bounds__(512) void scan1_kernel(
    const float* __restrict__ xp, const float* __restrict__ dtb,
    const float* __restrict__ Bmb, const float* __restrict__ lamb,
    const float2* __restrict__ cst,
    const float* __restrict__ Alog, float* __restrict__ hend, float* __restrict__ Pp)
{
  __shared__ float Bst[TC+1][DS];
  __shared__ float lst[TC];
  const int t = threadIdx.x;
  const int d  = t >> 1;
  const int s0 = (t & 1) * 8;
  const int c = blockIdx.x & (NC-1);
  const int b = blockIdx.x >> 7;
  const size_t bL = (size_t)b*SEQL;
  const int t0 = c*TC;
  const int id = blockIdx.x*256 + d;

  for (int e=t; e<(TC+1)*DS; e+=512){
    const int j = e >> 4, s = e & 15;
    const int trow = t0 - 1 + j;
    Bst[j][s] = (trow >= 0) ? Bmb[(bL + trow)*DS + s] : 0.0f;
  }
  if (t < TC) lst[t] = lamb[bL + t0 + t];
  __syncthreads();
  if (t < 136){
    const int j = t >> 3, f = t & 7;
    const int trow = t0 - 1 + j;
    if (trow >= 0){
      const float2 cs = cst[((size_t)(bL + trow))*8 + f];
      const float e0 = Bst[j][2*f], o0 = Bst[j][2*f+1];
      Bst[j][2*f]   = e0*cs.x - o0*cs.y;
      Bst[j][2*f+1] = e0*cs.y + o0*cs.x;
    }
  }
  __syncthreads();

  float A[8];
  #pragma unroll
  for (int s=0;s<8;s++) A[s] = fminf(-expf(Alog[d*DS + s0 + s]), -1e-4f);
  float h[8], P[8], Bprev[8];
  #pragma unroll
  for (int s=0;s<8;s++){ h[s]=0.0f; P[s]=1.0f; }
  float xpm1;
  int tstart;
  if (t0 > 0){
    #pragma unroll
    for (int s=0;s<8;s++) Bprev[s] = Bst[0][s0+s];
    xpm1 = xp[(bL + t0 - 1)*DI + d];
    tstart = t0;
  } else {
    const size_t rowE = bL*DI + d;
    const float dtv = dtb[rowE];
    const float xpv = xp[rowE];
    #pragma unroll
    for (int s=0;s<8;s++){
      const float a = __expf(A[s]*dtv);
      h[s] = dtv*(Bst[1][s0+s]*xpv);
      P[s] *= a;
      Bprev[s] = Bst[1][s0+s];
    }
    xpm1 = xpv;
    tstart = 1;
  }
  for (int tt=tstart; tt<t0+TC; ++tt){
    const size_t rowE = (bL + tt)*DI + d;
    const float dtv = dtb[rowE];
    const float xpv = xp[rowE];
    const float lamv = lst[tt - t0];
    const int j = tt - t0 + 1;
    const float dl = dtv*lamv;
    const float dml = dtv - dl;
    #pragma unroll
    for (int s=0;s<8;s++){
      const float a = __expf(A[s]*dtv);
      const float Bc = Bst[j][s0+s];
      const float u = fmaf(dml*a, Bprev[s]*xpm1, dl*(Bc*xpv));
      h[s] = fmaf(a, h[s], u);
      P[s] *= a;
      Bprev[s] = Bc;
    }
    xpm1 = xpv;
  }
  store8(hend + (size_t)id*DS + s0, h);
  store8(Pp   + (size_t)id*DS + s0, P);
}

// ---------------- scan phase 2: sequential chunk combine ----------------
__global__ __launch_bounds__(256) void scan2_kernel(float* __restrict__ hend, const float* __restrict__ Pp){
  const int id = blockIdx.x*256 + threadIdx.x;   // BSZ*DI*DS
  const int s = id & 15, d = (id >> 4) & (DI-1), b = id >> 12;
  float H = 0.0f;
  #pragma unroll 4
  for (int c=0;c<NC;c++){
    const size_t ix = (((size_t)(b*NC + c))*DI + d)*DS + s;
    const float he = hend[ix], p = Pp[ix];
    hend[ix] = H;          // chunk-initial state
    H = fmaf(p, H, he);
  }
}

// ---------------- scan phase 3 + out_proj + residual (s-split, 512 threads) ----------------
__global__ __launch_bounds__(512) void scan3post_kernel(
    const float* __restrict__ xp, const float* __restrict__ dtb,
    const float* __restrict__ Bmb, const float* __restrict__ Cmb,
    const float* __restrict__ lamb, const float* __restrict__ zsb,
    const float2* __restrict__ cst,
    const float* __restrict__ Alog, const float* __restrict__ Dv,
    const float* __restrict__ Hin, const float* __restrict__ Wo,
    float* __restrict__ hb)
{
  __shared__ float Bst[TC+1][DS];
  __shared__ float Cst[TC][DS];
  __shared__ float lst[TC];
  __shared__ float ys[TC][DI+4];
  const int t = threadIdx.x;
  const int d  = t >> 1;
  const int sh = t & 1;
  const int s0 = sh * 8;
  const int c = blockIdx.x & (NC-1);
  const int b = blockIdx.x >> 7;
  const size_t bL = (size_t)b*SEQL;
  const int t0 = c*TC;
  const int id = blockIdx.x*256 + d;

  for (int e=t; e<(TC+1)*DS; e+=512){
    const int j = e >> 4, s = e & 15;
    const int trow = t0 - 1 + j;
    Bst[j][s] = (trow >= 0) ? Bmb[(bL + trow)*DS + s] : 0.0f;
    if (j < TC) Cst[j][s] = Cmb[(bL + t0 + j)*DS + s];
  }
  if (t < TC) lst[t] = lamb[bL + t0 + t];
  __syncthreads();
  if (t < 264){
    if (t < 136){
      const int j = t >> 3, f = t & 7;
      const int trow = t0 - 1 + j;
      if (trow >= 0){
        const float2 cs = cst[((size_t)(bL + trow))*8 + f];
        const float e0 = Bst[j][2*f], o0 = Bst[j][2*f+1];
        Bst[j][2*f]   = e0*cs.x - o0*cs.y;
        Bst[j][2*f+1] = e0*cs.y + o0*cs.x;
      }
    } else {
      const int e2 = t - 136;
      const int j = e2 >> 3, f = e2 & 7;
      const float2 cs = cst[((size_t)(bL + t0 + j))*8 + f];
      const float e0 = Cst[j][2*f], o0 = Cst[j][2*f+1];
      Cst[j][2*f]   = e0*cs.x - o0*cs.y;
      Cst[j][2*f+1] = e0*cs.y + o0*cs.x;
    }
  }
  __syncthreads();

  float A[8];
  #pragma unroll
  for (int s=0;s<8;s++) A[s] = fminf(-expf(Alog[d*DS + s0 + s]), -1e-4f);
  const float dvp = Dv[d];
  float h[8], Bprev[8];
  load8(Hin + (size_t)id*DS + s0, h);
  float xpm1;
  int tstart;
  if (t0 > 0){
    #pragma unroll
    for (int s=0;s<8;s++) Bprev[s] = Bst[0][s0+s];
    xpm1 = xp[(bL + t0 - 1)*DI + d];
    tstart = t0;
  } else {
    const size_t rowE = bL*DI + d;
    const float dtv = dtb[rowE];
    const float xpv = xp[rowE];
    float y = 0.0f;
    #pragma unroll
    for (int s=0;s<8;s++){
      h[s] = dtv*(Bst[1][s0+s]*xpv);   // h starts at 0
      y = fmaf(h[s], Cst[0][s0+s], y);
      Bprev[s] = Bst[1][s0+s];
    }
    const float ytot = y + __shfl_xor(y, 1, 64);
    if (sh == 0) ys[0][d] = (ytot + xpv*dvp)*zsb[rowE];
    xpm1 = xpv;
    tstart = 1;
  }
  for (int tt=tstart; tt<t0+TC; ++tt){
    const size_t rowE = (bL + tt)*DI + d;
    const float dtv = dtb[rowE];
    const float xpv = xp[rowE];
    const float lamv = lst[tt - t0];
    const int j = tt - t0;
    const float dl = dtv*lamv;
    const float dml = dtv - dl;
    float y = 0.0f;
    #pragma unroll
    for (int s=0;s<8;s++){
      const float a = __expf(A[s]*dtv);
      const float Bc = Bst[j+1][s0+s];
      const float u = fmaf(dml*a, Bprev[s]*xpm1, dl*(Bc*xpv));
      h[s] = fmaf(a, h[s], u);
      y = fmaf(h[s], Cst[j][s0+s], y);
      Bprev[s] = Bc;
    }
    const float ytot = y + __shfl_xor(y, 1, 64);
    if (sh == 0) ys[j][d] = (ytot + xpv*dvp)*zsb[rowE];
    xpm1 = xpv;
  }
  __syncthreads();

  // out_proj (16 rows x 128 cols, K=256) + residual into hb; 512 threads, 4 cols each
  {
    const int r  = t >> 5;         // 0..15
    const int cg = t & 31;
    const int c0 = cg*4;
    float acc[4] = {0.0f,0.0f,0.0f,0.0f};
    for (int k=0;k<DI;k+=4){
      const float4 yv = *(const float4*)&ys[r][k];
      const float yy[4] = {yv.x, yv.y, yv.z, yv.w};
      #pragma unroll
      for (int j=0;j<4;j++){
        const float4 wa = *(const float4*)&Wo[(size_t)(k+j)*DM + c0];
        acc[0]=fmaf(yy[j],wa.x,acc[0]); acc[1]=fmaf(yy[j],wa.y,acc[1]);
        acc[2]=fmaf(yy[j],wa.z,acc[2]); acc[3]=fmaf(yy[j],wa.w,acc[3]);
      }
    }
    const size_t row = bL + t0 + r;
    float4 h0 = *(const float4*)&hb[row*DM + c0];
    h0.x+=acc[0]; h0.y+=acc[1]; h0.z+=acc[2]; h0.w+=acc[3];
    *(float4*)&hb[row*DM + c0] = h0;
  }
}

// ---------------- final LN + landmark attention (one block per batch) ----------------
__global__ __launch_bounds__(256) void attn_kernel(
    const float* __restrict__ hb, const float* __restrict__ sk,
    const float* __restrict__ hw,
    const float* __restrict__ fnw, const float* __restrict__ fnb,
    const float* __restrict__ WQ, const float* __restrict__ bQ,
    const float* __restrict__ WK, const float* __restrict__ bK,
    const float* __restrict__ WV, const float* __restrict__ bV,
    const float* __restrict__ WO, const float* __restrict__ bO,
    float* __restrict__ outp)
{
  __shared__ float kv[KLM][DM+4];
  __shared__ float mo[DM];
  __shared__ float Qs[DM];
  __shared__ float qk[NHEAD][DM];
  __shared__ float bterm[NHEAD];
  __shared__ float sc[NHEAD][KLM];
  __shared__ float pbar[NHEAD][DM];
  __shared__ float attno[DM];
  __shared__ int idxl[KLM];
  __shared__ int redcnt[2][4];
  __shared__ int eqc[8][4], gtc[8][4];
  __shared__ float red_f[4];

  const int b = blockIdx.x;
  const int t = threadIdx.x;
  const int lane = t & 63, w = t >> 6;

  const float* hwp = hw + (size_t)b*SEQL;
  unsigned vb[8];
  #pragma unroll
  for (int q=0;q<8;q++) vb[q] = __float_as_uint(hwp[q*256 + t]);

  unsigned kth = 0u;
  for (int bit=31; bit>=0; --bit){
    const unsigned cand = kth | (1u << bit);
    int c0 = 0;
    #pragma unroll
    for (int q=0;q<8;q++) c0 += __popcll(__ballot(vb[q] >= cand));
    const int par = bit & 1;
    if (lane == 0) redcnt[par][w] = c0;
    __syncthreads();
    const int tot = redcnt[par][0]+redcnt[par][1]+redcnt[par][2]+redcnt[par][3];
    if (tot >= KLM) kth = cand;
  }

  unsigned long long beq[8], bgt[8];
  #pragma unroll
  for (int q=0;q<8;q++){
    beq[q] = __ballot(vb[q] == kth);
    bgt[q] = __ballot(vb[q] >  kth);
  }
  if (lane == 0){
    #pragma unroll
    for (int q=0;q<8;q++){ eqc[q][w] = __popcll(beq[q]); gtc[q][w] = __popcll(bgt[q]); }
  }
  __syncthreads();
  {
    int gtTot = 0;
    #pragma unroll
    for (int q=0;q<8;q++) gtTot += gtc[q][0]+gtc[q][1]+gtc[q][2]+gtc[q][3];
    const int need_eq = KLM - gtTot;
    const unsigned long long lmask = (lane==0) ? 0ull : ((~0ull) >> (64-lane));
    int eqPfx = 0, gtPfx = 0;
    #pragma unroll
    for (int q=0;q<8;q++){
      int eqWP = 0, gtWP = 0;
      for (int w2=0; w2<w; ++w2){ eqWP += eqc[q][w2]; gtWP += gtc[q][w2]; }
      const int eqBefore = eqPfx + eqWP + __popcll(beq[q] & lmask);
      const int gtBefore = gtPfx + gtWP + __popcll(bgt[q] & lmask);
      if (vb[q] > kth){
        const int pos = gtBefore + min(eqBefore, need_eq);
        if (pos < KLM) idxl[pos] = q*256 + t;
      } else if (vb[q] == kth && eqBefore < need_eq){
        const int pos = gtBefore + eqBefore;
        if (pos < KLM) idxl[pos] = q*256 + t;
      }
      eqPfx += eqc[q][0]+eqc[q][1]+eqc[q][2]+eqc[q][3];
      gtPfx += gtc[q][0]+gtc[q][1]+gtc[q][2]+gtc[q][3];
    }
  }
  __syncthreads();

  {
    const float* hr = hb + ((size_t)b*SEQL + (SEQL-1))*DM;
    const float hv = (t < DM) ? hr[t] : 0.0f;
    const float ssum = block_sum256(hv, red_f);
    const float mean = ssum*(1.0f/DM);
    const float dv = (t < DM) ? (hv - mean) : 0.0f;
    const float vsum = block_sum256(dv*dv, red_f);
    const float inv = 1.0f/sqrtf(vsum*(1.0f/DM) + 1e-5f);
    if (t < DM) mo[t] = dv*inv*fnw[t] + fnb[t];
  }
  __syncthreads();

  for (int e=t; e<KLM*DM; e+=256){
    const int j = e >> 7, cc = e & (DM-1);
    kv[j][cc] = sk[((size_t)b*SEQL + idxl[j])*DM + cc];
  }
  __syncthreads();

  if (t < DM){
    float a = bQ[t];
    #pragma unroll 4
    for (int k=0;k<DM;k++) a = fmaf(mo[k], WQ[(size_t)k*DM + t], a);
    Qs[t] = a;
  }
  __syncthreads();
  for (int e=t; e<NHEAD*DM; e+=256){
    const int hh = e >> 7, m = e & (DM-1);
    const int c0 = hh*DHEAD;
    float a = 0.0f;
    #pragma unroll
    for (int cc=0; cc<DHEAD; cc++) a = fmaf(WK[(size_t)m*DM + c0 + cc], Qs[c0+cc], a);
    qk[hh][m] = a;
  }
  if (t < NHEAD){
    float a = 0.0f;
    for (int cc=0; cc<DHEAD; cc++) a += bK[t*DHEAD+cc]*Qs[t*DHEAD+cc];
    bterm[t] = a;
  }
  __syncthreads();
  for (int e=t; e<NHEAD*KLM; e+=256){
    const int hh = e/KLM, j = e - hh*KLM;
    float a = bterm[hh];
    for (int m=0;m<DM;m+=4){
      const float4 kvv = *(const float4*)&kv[j][m];
      const float4 qv  = *(const float4*)&qk[hh][m];
      a = fmaf(kvv.x,qv.x,a); a = fmaf(kvv.y,qv.y,a);
      a = fmaf(kvv.z,qv.z,a); a = fmaf(kvv.w,qv.w,a);
    }
    sc[hh][j] = a*0.17677669529663687f;
  }
  __syncthreads();
  {
    const int hh = w;
    const float v0 = (lane < KLM) ? sc[hh][lane] : -3.0e38f;
    const float v1 = (lane+64 < KLM) ? sc[hh][lane+64] : -3.0e38f;
    float mx = fmaxf(v0, v1);
    #pragma unroll
    for (int o2=32;o2>0;o2>>=1) mx = fmaxf(mx, __shfl_xor(mx,o2,64));
    const float e0 = (lane < KLM) ? expf(v0-mx) : 0.0f;
    const float e1 = (lane+64 < KLM) ? expf(v1-mx) : 0.0f;
    float sm = e0+e1;
    #pragma unroll
    for (int o2=32;o2>0;o2>>=1) sm += __shfl_xor(sm,o2,64);
    const float inv2 = 1.0f/sm;
    if (lane < KLM) sc[hh][lane] = e0*inv2;
    if (lane+64 < KLM) sc[hh][lane+64] = e1*inv2;
  }
  __syncthreads();
  for (int e=t; e<NHEAD*DM; e+=256){
    const int hh = e >> 7, m = e & (DM-1);
    float a = 0.0f;
    #pragma unroll 4
    for (int j=0;j<KLM;j++) a = fmaf(sc[hh][j], kv[j][m], a);
    pbar[hh][m] = a;
  }
  __syncthreads();
  if (t < DM){
    const int hh = t >> 5;
    float a = bV[t];
    for (int m=0;m<DM;m+=4){
      const float4 pv = *(const float4*)&pbar[hh][m];
      a = fmaf(pv.x, WV[(size_t)(m+0)*DM + t], a);
      a = fmaf(pv.y, WV[(size_t)(m+1)*DM + t], a);
      a = fmaf(pv.z, WV[(size_t)(m+2)*DM + t], a);
      a = fmaf(pv.w, WV[(size_t)(m+3)*DM + t], a);
    }
    attno[t] = a;
  }
  __syncthreads();
  if (t < DM){
    float a = bO[t];
    #pragma unroll 4
    for (int c2=0;c2<DM;c2++) a = fmaf(attno[c2], WO[(size_t)c2*DM + t], a);
    outp[(size_t)b*DM + t] = a;
  }
}

extern "C" void kernel_launch(void* const* d_in, const int* in_sizes, int n_in,
                              void* d_out, int out_size, void* d_ws, size_t ws_size,
                              hipStream_t stream)
{
  (void)in_sizes; (void)n_in; (void)out_size; (void)ws_size;
  const float* x    = (const float*)d_in[0];
  const float* hw   = (const float*)d_in[1];
  const float* embW = (const float*)d_in[2];
  const float* embB = (const float*)d_in[3];
  const float* skW  = (const float*)d_in[4];
  const float* skB  = (const float*)d_in[5];
  const float* inW  = (const float*)d_in[6];
  const float* xpW  = (const float*)d_in[7];
  const float* dtW  = (const float*)d_in[8];
  const float* dtB  = (const float*)d_in[9];
  const float* Alog = (const float*)d_in[10];
  const float* Bb   = (const float*)d_in[11];
  const float* Cb   = (const float*)d_in[12];
  const float* Bnw  = (const float*)d_in[13];
  const float* Cnw  = (const float*)d_in[14];
  const float* rf   = (const float*)d_in[15];
  const float* Dpar = (const float*)d_in[16];
  const float* outW = (const float*)d_in[17];
  const float* lnW  = (const float*)d_in[18];
  const float* lnB  = (const float*)d_in[19];
  const float* fnW  = (const float*)d_in[20];
  const float* fnB  = (const float*)d_in[21];
  const float* WQ = (const float*)d_in[22]; const float* bQ = (const float*)d_in[23];
  const float* WK = (const float*)d_in[24]; const float* bK = (const float*)d_in[25];
  const float* WV = (const float*)d_in[26]; const float* bV = (const float*)d_in[27];
  const float* WO = (const float*)d_in[28]; const float* bO = (const float*)d_in[29];

  float* ws = (float*)d_ws;
  size_t off = 0;
  float* hb   = ws + off; off += (size_t)BSZ*SEQL*DM;
  float* sk   = ws + off; off += (size_t)BSZ*SEQL*DM;
  float* xpb  = ws + off; off += (size_t)BSZ*SEQL*DI;
  float* zsb  = ws + off; off += (size_t)BSZ*SEQL*DI;
  float* dtb  = ws + off; off += (size_t)BSZ*SEQL*DI;
  float* Bmb  = ws + off; off += (size_t)BSZ*SEQL*DS;
  float* Cmb  = ws + off; off += (size_t)BSZ*SEQL*DS;
  float* lamb = ws + off; off += (size_t)BSZ*SEQL;
  float* mdtb = ws + off; off += (size_t)BSZ*SEQL;
  float* hend = ws + off; off += (size_t)BSZ*NC*DI*DS;
  float* Ppb  = ws + off; off += (size_t)BSZ*NC*DI*DS;
  float2* cst = (float2*)(ws + off);                     // BSZ*SEQL*8 float2

  embed_kernel<<<BSZ*SEQL/EROWS, 256, 0, stream>>>(x, hw, embW, embB, skW, skB, hb, sk);

  for (int i=0;i<NL;i++){
    ln_inproj_kernel<<<BSZ*SEQL/PROWS*4, 256, 0, stream>>>(hb,
        inW + (size_t)i*DM*2*DI, lnW + i*DM, lnB + i*DM, xpb, zsb);
    xproj_kernel<<<BSZ*SEQL/PROWS, 256, 0, stream>>>(xpb,
        xpW + (size_t)i*DI*34, dtW + (size_t)i*DI, dtB + (size_t)i*DI,
        Bb + i*DS, Cb + i*DS, Bnw + i*DS, Cnw + i*DS,
        dtb, Bmb, Cmb, lamb, mdtb);
    cumsum_cs_kernel<<<BSZ, 256, 0, stream>>>(mdtb, rf + i*8, cst);
    scan1_kernel<<<BSZ*NC, 512, 0, stream>>>(xpb, dtb, Bmb, lamb, cst,
        Alog + (size_t)i*DI*DS, hend, Ppb);
    scan2_kernel<<<BSZ*DI*DS/256, 256, 0, stream>>>(hend, Ppb);
    scan3post_kernel<<<BSZ*NC, 512, 0, stream>>>(xpb, dtb, Bmb, Cmb, lamb, zsb, cst,
        Alog + (size_t)i*DI*DS, Dpar + (size_t)i*DI, hend,
        outW + (size_t)i*DI*DM, hb);
  }

  attn_kernel<<<BSZ, 256, 0, stream>>>(hb, sk, hw, fnW, fnB,
      WQ, bQ, WK, bK, WV, bV, WO, bO, (float*)d_out);
}

// Round 6
// 655.572 us; speedup vs baseline: 1.2595x; 1.2595x over previous
//
#include <hip/hip_runtime.h>
#include <hip/hip_fp16.h>
#include <math.h>

#define BSZ   4
#define SEQL  2048
#define DIN   40
#define DM    128
#define DI    256
#define DS    16
#define NL    4
#define NHEAD 4
#define DHEAD 32
#define KLM   100
#define NC    128       // chunks per sequence
#define TC    16        // SEQL / NC
#define NROWS 8         // rows per pre block
#define EROWS 16

__device__ __forceinline__ float sigmoidf_(float x){ return 1.0f/(1.0f + expf(-x)); }
__device__ __forceinline__ float siluf_(float x){ return x/(1.0f + expf(-x)); }
__device__ __forceinline__ float softplusf_(float x){ return fmaxf(x,0.0f) + log1pf(expf(-fabsf(x))); }

__device__ __forceinline__ float block_sum256(float v, float* red){
  #pragma unroll
  for (int o=32;o>0;o>>=1) v += __shfl_down(v,o,64);
  __syncthreads();
  if ((threadIdx.x & 63)==0) red[threadIdx.x>>6] = v;
  __syncthreads();
  return red[0]+red[1]+red[2]+red[3];
}
__device__ __forceinline__ void load8(const float* p, float* r){
  const float4* q = (const float4*)p;
  float4 a=q[0], b=q[1];
  r[0]=a.x;r[1]=a.y;r[2]=a.z;r[3]=a.w; r[4]=b.x;r[5]=b.y;r[6]=b.z;r[7]=b.w;
}
__device__ __forceinline__ void store8(float* p, const float* r){
  float4* q = (float4*)p;
  q[0]=make_float4(r[0],r[1],r[2],r[3]);  q[1]=make_float4(r[4],r[5],r[6],r[7]);
}
__device__ __forceinline__ void load16(const float* p, float* r){
  load8(p, r); load8(p+8, r+8);
}
__device__ __forceinline__ void store16(float* p, const float* r){
  store8(p, r); store8(p+8, r+8);
}

// ---------------- embed: 16 rows/block ----------------
__global__ __launch_bounds__(256) void embed_kernel(
    const float* __restrict__ x, const float* __restrict__ hw,
    const float* __restrict__ eW, const float* __restrict__ eb,
    const float* __restrict__ sW, const float* __restrict__ sb,
    float* __restrict__ hb, float* __restrict__ sk)
{
  __shared__ float xr[EROWS][DIN];
  const int t = threadIdx.x;
  const size_t R0 = (size_t)blockIdx.x * EROWS;
  for (int e=t; e<EROWS*DIN; e+=256) ((float*)xr)[e] = x[R0*DIN + e];
  __syncthreads();
  const int c = t & (DM-1), g = t >> 7;
  float ae[8], as[8];
  #pragma unroll
  for (int j=0;j<8;j++){ ae[j]=0.0f; as[j]=0.0f; }
  for (int k=0;k<DIN;k++){
    const float we  = eW[(size_t)k*DM + c];
    const float ws_ = sW[(size_t)k*DM + c];
    #pragma unroll
    for (int j=0;j<8;j++){
      const float xv = xr[g*8+j][k];
      ae[j] = fmaf(xv, we, ae[j]);
      as[j] = fmaf(xv, ws_, as[j]);
    }
  }
  const float ebv = eb[c], sbv = sb[c];
  #pragma unroll
  for (int j=0;j<8;j++){
    const size_t R = R0 + g*8 + j;
    const float w = hw[R];
    hb[R*DM + c] = (ae[j]+ebv)*w;
    sk[R*DM + c] = (as[j]+sbv)*w;
  }
}

// ---------------- fused pre: LN -> in_proj -> silu -> x_proj -> B/C/dt/lam ----------------
// 8 rows/block, 256 thr, 1024 blocks. fp16 xp/z out; no per-element dt out.
__global__ __launch_bounds__(256) void pre_kernel(
    const float* __restrict__ hb,
    const float* __restrict__ Wi, const float* __restrict__ Wx,
    const float* __restrict__ Wdt, const float* __restrict__ bdt,
    const float* __restrict__ Bb, const float* __restrict__ Cb,
    const float* __restrict__ Bnw, const float* __restrict__ Cnw,
    const float* __restrict__ lnw, const float* __restrict__ lnb,
    __half* __restrict__ xph, __half* __restrict__ zsh,
    float* __restrict__ dtin, float* __restrict__ Shalf,
    float* __restrict__ Bmb, float* __restrict__ Cmb,
    float* __restrict__ lamb, float* __restrict__ mdtb)
{
  __shared__ float xin[NROWS][DM+4];
  __shared__ float xps[NROWS][DI+4];
  __shared__ float spl[NROWS][40];
  __shared__ float pr[NROWS][4];

  const int t = threadIdx.x;
  const size_t R0 = (size_t)blockIdx.x * NROWS;

  { // LayerNorm: 32 threads per row
    const int r = t >> 5, j = t & 31;
    const float4 v = ((const float4*)(hb + (R0 + r)*DM))[j];
    float s = v.x+v.y+v.z+v.w;
    #pragma unroll
    for (int o=16;o>0;o>>=1) s += __shfl_xor(s,o,32);
    const float m = s*(1.0f/DM);
    const float dx=v.x-m, dy=v.y-m, dz=v.z-m, dw=v.w-m;
    float ss = dx*dx+dy*dy+dz*dz+dw*dw;
    #pragma unroll
    for (int o=16;o>0;o>>=1) ss += __shfl_xor(ss,o,32);
    const float inv = 1.0f/sqrtf(ss*(1.0f/DM) + 1e-5f);
    const int c = j*4;
    xin[r][c+0] = dx*inv*lnw[c+0] + lnb[c+0];
    xin[r][c+1] = dy*inv*lnw[c+1] + lnb[c+1];
    xin[r][c+2] = dz*inv*lnw[c+2] + lnb[c+2];
    xin[r][c+3] = dw*inv*lnw[c+3] + lnb[c+3];
  }
  __syncthreads();

  { // xz = xin @ Wi; thread t owns cols 2t, 2t+1
    float2 a[NROWS];
    #pragma unroll
    for (int r=0;r<NROWS;r++){ a[r].x=0.0f; a[r].y=0.0f; }
    for (int k=0;k<DM;k+=4){
      const float2 w0 = *(const float2*)&Wi[(size_t)(k+0)*(2*DI) + 2*t];
      const float2 w1 = *(const float2*)&Wi[(size_t)(k+1)*(2*DI) + 2*t];
      const float2 w2 = *(const float2*)&Wi[(size_t)(k+2)*(2*DI) + 2*t];
      const float2 w3 = *(const float2*)&Wi[(size_t)(k+3)*(2*DI) + 2*t];
      #pragma unroll
      for (int r=0;r<NROWS;r++){
        const float4 xv = *(const float4*)&xin[r][k];
        a[r].x = fmaf(xv.x,w0.x,a[r].x); a[r].y = fmaf(xv.x,w0.y,a[r].y);
        a[r].x = fmaf(xv.y,w1.x,a[r].x); a[r].y = fmaf(xv.y,w1.y,a[r].y);
        a[r].x = fmaf(xv.z,w2.x,a[r].x); a[r].y = fmaf(xv.z,w2.y,a[r].y);
        a[r].x = fmaf(xv.w,w3.x,a[r].x); a[r].y = fmaf(xv.w,w3.y,a[r].y);
      }
    }
    if (t < 128){
      #pragma unroll
      for (int r=0;r<NROWS;r++){
        const float sx = siluf_(a[r].x), sy = siluf_(a[r].y);
        xps[r][2*t] = sx; xps[r][2*t+1] = sy;
        *(__half2*)&xph[(R0+r)*DI + 2*t] =
            __halves2half2(__float2half_rn(sx), __float2half_rn(sy));
      }
    } else {
      const int zc = 2*t - 2*DI + DI;   // cols 2t in [256,512) -> z col 2t-256
      #pragma unroll
      for (int r=0;r<NROWS;r++){
        const float sx = siluf_(a[r].x), sy = siluf_(a[r].y);
        *(__half2*)&zsh[(R0+r)*DI + zc] =
            __halves2half2(__float2half_rn(sx), __float2half_rn(sy));
      }
    }
  }
  __syncthreads();

  // sp = xp @ Wx.  136 tasks = 8 rows x 17 col-pairs
  if (t < 136){
    const int r = t & 7, op = t >> 3;
    float ax=0.0f, ay=0.0f;
    for (int k=0;k<DI;k+=4){
      const float4 xv = *(const float4*)&xps[r][k];
      const float2 w0 = *(const float2*)&Wx[(size_t)(k+0)*34 + 2*op];
      const float2 w1 = *(const float2*)&Wx[(size_t)(k+1)*34 + 2*op];
      const float2 w2 = *(const float2*)&Wx[(size_t)(k+2)*34 + 2*op];
      const float2 w3 = *(const float2*)&Wx[(size_t)(k+3)*34 + 2*op];
      ax = fmaf(xv.x,w0.x,ax); ay = fmaf(xv.x,w0.y,ay);
      ax = fmaf(xv.y,w1.x,ax); ay = fmaf(xv.y,w1.y,ay);
      ax = fmaf(xv.z,w2.x,ax); ay = fmaf(xv.z,w2.y,ay);
      ax = fmaf(xv.w,w3.x,ax); ay = fmaf(xv.w,w3.y,ay);
    }
    spl[r][2*op] = ax; spl[r][2*op+1] = ay;
  }
  __syncthreads();

  { // B/C rms-norm: 256 tasks = 2 halves x 8 rows x 16 states
    const int half = t >> 7;
    const int r2 = (t >> 4) & 7, s2 = t & 15;
    const float* bias = half ? Cb : Bb;
    const float* wn   = half ? Cnw : Bnw;
    const float v = spl[r2][half*DS + s2] + bias[s2];
    float ss = v*v;
    #pragma unroll
    for (int o=8;o>0;o>>=1) ss += __shfl_xor(ss,o,16);
    const float inv = 1.0f/sqrtf(ss*(1.0f/DS) + 1.1920929e-07f);
    (half ? Cmb : Bmb)[(R0+r2)*DS + s2] = v*inv*wn[s2];
  }

  { // dt: thread = d; loop 8 rows; accumulate half-chunk sum; no per-element store
    const int lane = t & 63, w = t >> 6;
    const float wdt = Wdt[t], bdtv = bdt[t];
    float Sd = 0.0f;
    #pragma unroll
    for (int r=0;r<NROWS;r++){
      const float dval = softplusf_(fmaf(spl[r][32], wdt, bdtv));
      Sd += dval;
      float s = dval;
      #pragma unroll
      for (int o=32;o>0;o>>=1) s += __shfl_xor(s,o,64);
      if (lane==0) pr[r][w] = s;
    }
    Shalf[(size_t)blockIdx.x * DI + t] = Sd;
    if (t < NROWS){
      lamb[R0+t] = sigmoidf_(spl[t][33]);
      dtin[R0+t] = spl[t][32];
    }
  }
  __syncthreads();
  if (t < NROWS)
    mdtb[R0+t] = (pr[t][0]+pr[t][1]+pr[t][2]+pr[t][3])*(1.0f/DI);
}

// ---------------- cumsum (f64) + cos/sin table ----------------
__global__ __launch_bounds__(256) void cumsum_cs_kernel(
    const float* __restrict__ mdt, const float* __restrict__ rf,
    float2* __restrict__ cst)
{
  __shared__ double csum[SEQL];
  __shared__ double wsum[4];
  __shared__ double fqs[8];
  const int b = blockIdx.x, t = threadIdx.x;
  const int lane = t & 63, w = t >> 6;
  if (t < 8){
    const double xfr = (double)rf[t];
    fqs[t] = fmax(xfr, 0.0) + log1p(exp(-fabs(xfr)));
  }
  const float* p = mdt + (size_t)b*SEQL + (size_t)t*8;
  double v[8]; double s = 0.0;
  #pragma unroll
  for (int q=0;q<8;q++){ v[q] = (double)p[q]; s += v[q]; }
  double sc = s;
  #pragma unroll
  for (int o=1;o<64;o<<=1){
    const double nb = __shfl_up(sc, o, 64);
    if (lane >= o) sc += nb;
  }
  if (lane==63) wsum[w] = sc;
  __syncthreads();
  double woff = 0.0;
  for (int j=0;j<w;j++) woff += wsum[j];
  double run = woff + sc - s;
  #pragma unroll
  for (int q=0;q<8;q++){ run += v[q]; csum[t*8+q] = run; }
  __syncthreads();

  const double TWO_PI = 6.283185307179586;
  const double INV2PI = 0.15915494309189535;
  for (int j=0;j<8;j++){
    const int rloc = j*256 + t;
    const double ab = csum[rloc];
    float2 o8[8];
    #pragma unroll
    for (int f=0; f<8; f++){
      const double ang = ab * fqs[f];
      const double red = ang - floor(ang*INV2PI)*TWO_PI;
      float sa, ca;
      __sincosf((float)red, &sa, &ca);
      o8[f] = make_float2(ca, sa);
    }
    float4* dst = (float4*)&cst[((size_t)b*SEQL + rloc)*8];
    dst[0] = make_float4(o8[0].x,o8[0].y,o8[1].x,o8[1].y);
    dst[1] = make_float4(o8[2].x,o8[2].y,o8[3].x,o8[3].y);
    dst[2] = make_float4(o8[4].x,o8[4].y,o8[5].x,o8[5].y);
    dst[3] = make_float4(o8[6].x,o8[6].y,o8[7].x,o8[7].y);
  }
}

// ---------------- scan phase 1 (s-split, 512 threads; no Pp; dt recompute) ----------------
__global__ __launch_bounds__(512) void scan1_kernel(
    const __half* __restrict__ xph, const float* __restrict__ dtin,
    const float* __restrict__ Wdt, const float* __restrict__ bdt,
    const float* __restrict__ Bmb, const float* __restrict__ lamb,
    const float2* __restrict__ cst,
    const float* __restrict__ Alog, float* __restrict__ hend)
{
  __shared__ float Bst[TC+1][DS];
  __shared__ float lst[TC];
  __shared__ float dst[TC];
  const int t = threadIdx.x;
  const int d  = t >> 1;
  const int s0 = (t & 1) * 8;
  const int c = blockIdx.x & (NC-1);
  const int b = blockIdx.x >> 7;
  const size_t bL = (size_t)b*SEQL;
  const int t0 = c*TC;
  const int id = blockIdx.x*256 + d;

  for (int e=t; e<(TC+1)*DS; e+=512){
    const int j = e >> 4, s = e & 15;
    const int trow = t0 - 1 + j;
    Bst[j][s] = (trow >= 0) ? Bmb[(bL + trow)*DS + s] : 0.0f;
  }
  if (t < TC){
    lst[t] = lamb[bL + t0 + t];
    dst[t] = dtin[bL + t0 + t];
  }
  __syncthreads();
  if (t < 136){
    const int j = t >> 3, f = t & 7;
    const int trow = t0 - 1 + j;
    if (trow >= 0){
      const float2 cs = cst[((size_t)(bL + trow))*8 + f];
      const float e0 = Bst[j][2*f], o0 = Bst[j][2*f+1];
      Bst[j][2*f]   = e0*cs.x - o0*cs.y;
      Bst[j][2*f+1] = e0*cs.y + o0*cs.x;
    }
  }
  __syncthreads();

  float A[8];
  #pragma unroll
  for (int s=0;s<8;s++) A[s] = fminf(-expf(Alog[d*DS + s0 + s]), -1e-4f);
  const float wdt = Wdt[d], bdtv = bdt[d];
  float h[8], Bprev[8];
  #pragma unroll
  for (int s=0;s<8;s++) h[s]=0.0f;
  float xpm1;
  int tstart;
  if (t0 > 0){
    #pragma unroll
    for (int s=0;s<8;s++) Bprev[s] = Bst[0][s0+s];
    xpm1 = __half2float(xph[(bL + t0 - 1)*DI + d]);
    tstart = t0;
  } else {
    const size_t rowE = bL*DI + d;
    const float dtv = softplusf_(fmaf(dst[0], wdt, bdtv));
    const float xpv = __half2float(xph[rowE]);
    #pragma unroll
    for (int s=0;s<8;s++){
      h[s] = dtv*(Bst[1][s0+s]*xpv);
      Bprev[s] = Bst[1][s0+s];
    }
    xpm1 = xpv;
    tstart = 1;
  }
  for (int tt=tstart; tt<t0+TC; ++tt){
    const size_t rowE = (bL + tt)*DI + d;
    const float dtv = softplusf_(fmaf(dst[tt-t0], wdt, bdtv));
    const float xpv = __half2float(xph[rowE]);
    const float lamv = lst[tt - t0];
    const int j = tt - t0 + 1;
    const float dl = dtv*lamv;
    const float dml = dtv - dl;
    #pragma unroll
    for (int s=0;s<8;s++){
      const float a = __expf(A[s]*dtv);
      const float Bc = Bst[j][s0+s];
      const float u = fmaf(dml*a, Bprev[s]*xpm1, dl*(Bc*xpv));
      h[s] = fmaf(a, h[s], u);
      Bprev[s] = Bc;
    }
    xpm1 = xpv;
  }
  store8(hend + (size_t)id*DS + s0, h);
}

// ---------------- scan phase 2: parallel Kogge-Stone over chunks; P = exp(A*S) ----------------
__global__ __launch_bounds__(128) void scan2_kernel(
    float* __restrict__ hend, const float* __restrict__ Shalf,
    const float* __restrict__ Alog)
{
  __shared__ float hS[NC][DS+1];
  __shared__ float pS[NC][DS+1];
  const int c = threadIdx.x;
  const int d = blockIdx.x & (DI-1);
  const int b = blockIdx.x >> 8;
  const float S = Shalf[(size_t)(b*(SEQL/NROWS) + 2*c)*DI + d]
                + Shalf[(size_t)(b*(SEQL/NROWS) + 2*c + 1)*DI + d];
  float P[DS], h[DS];
  #pragma unroll
  for (int s=0;s<DS;s++){
    const float A = fminf(-expf(Alog[d*DS+s]), -1e-4f);
    P[s] = __expf(A*S);
  }
  load16(hend + (((size_t)(b*NC + c))*DI + d)*DS, h);
  #pragma unroll
  for (int s=0;s<DS;s++){ hS[c][s]=h[s]; pS[c][s]=P[s]; }
  __syncthreads();
  for (int off=1; off<NC; off<<=1){
    float hn[DS], pn[DS];
    const int src = c - off;
    if (src >= 0){
      #pragma unroll
      for (int s=0;s<DS;s++){ hn[s]=hS[src][s]; pn[s]=pS[src][s]; }
    }
    __syncthreads();
    if (src >= 0){
      #pragma unroll
      for (int s=0;s<DS;s++){
        h[s] = fmaf(P[s], hn[s], h[s]);
        P[s] *= pn[s];
        hS[c][s] = h[s]; pS[c][s] = P[s];
      }
    }
    __syncthreads();
  }
  float o[DS];
  if (c == 0){
    #pragma unroll
    for (int s=0;s<DS;s++) o[s] = 0.0f;
  } else {
    #pragma unroll
    for (int s=0;s<DS;s++) o[s] = hS[c-1][s];
  }
  store16(hend + (((size_t)(b*NC + c))*DI + d)*DS, o);
}

// ---------------- scan phase 3 + out_proj + residual (s-split; fp16; dt recompute) ----------------
__global__ __launch_bounds__(512) void scan3post_kernel(
    const __half* __restrict__ xph, const float* __restrict__ dtin,
    const float* __restrict__ Wdt, const float* __restrict__ bdt,
    const float* __restrict__ Bmb, const float* __restrict__ Cmb,
    const float* __restrict__ lamb, const __half* __restrict__ zsh,
    const float2* __restrict__ cst,
    const float* __restrict__ Alog, const float* __restrict__ Dv,
    const float* __restrict__ Hin, const float* __restrict__ Wo,
    float* __restrict__ hb)
{
  __shared__ float Bst[TC+1][DS];
  __shared__ float Cst[TC][DS];
  __shared__ float lst[TC];
  __shared__ float dst[TC];
  __shared__ float ys[TC][DI+4];
  const int t = threadIdx.x;
  const int d  = t >> 1;
  const int sh = t & 1;
  const int s0 = sh * 8;
  const int c = blockIdx.x & (NC-1);
  const int b = blockIdx.x >> 7;
  const size_t bL = (size_t)b*SEQL;
  const int t0 = c*TC;
  const int id = blockIdx.x*256 + d;

  for (int e=t; e<(TC+1)*DS; e+=512){
    const int j = e >> 4, s = e & 15;
    const int trow = t0 - 1 + j;
    Bst[j][s] = (trow >= 0) ? Bmb[(bL + trow)*DS + s] : 0.0f;
    if (j < TC) Cst[j][s] = Cmb[(bL + t0 + j)*DS + s];
  }
  if (t < TC){
    lst[t] = lamb[bL + t0 + t];
    dst[t] = dtin[bL + t0 + t];
  }
  __syncthreads();
  if (t < 264){
    if (t < 136){
      const int j = t >> 3, f = t & 7;
      const int trow = t0 - 1 + j;
      if (trow >= 0){
        const float2 cs = cst[((size_t)(bL + trow))*8 + f];
        const float e0 = Bst[j][2*f], o0 = Bst[j][2*f+1];
        Bst[j][2*f]   = e0*cs.x - o0*cs.y;
        Bst[j][2*f+1] = e0*cs.y + o0*cs.x;
      }
    } else {
      const int e2 = t - 136;
      const int j = e2 >> 3, f = e2 & 7;
      const float2 cs = cst[((size_t)(bL + t0 + j))*8 + f];
      const float e0 = Cst[j][2*f], o0 = Cst[j][2*f+1];
      Cst[j][2*f]   = e0*cs.x - o0*cs.y;
      Cst[j][2*f+1] = e0*cs.y + o0*cs.x;
    }
  }
  __syncthreads();

  float A[8];
  #pragma unroll
  for (int s=0;s<8;s++) A[s] = fminf(-expf(Alog[d*DS + s0 + s]), -1e-4f);
  const float wdt = Wdt[d], bdtv = bdt[d];
  const float dvp = Dv[d];
  float h[8], Bprev[8];
  load8(Hin + (size_t)id*DS + s0, h);
  float xpm1;
  int tstart;
  if (t0 > 0){
    #pragma unroll
    for (int s=0;s<8;s++) Bprev[s] = Bst[0][s0+s];
    xpm1 = __half2float(xph[(bL + t0 - 1)*DI + d]);
    tstart = t0;
  } else {
    const size_t rowE = bL*DI + d;
    const float dtv = softplusf_(fmaf(dst[0], wdt, bdtv));
    const float xpv = __half2float(xph[rowE]);
    float y = 0.0f;
    #pragma unroll
    for (int s=0;s<8;s++){
      h[s] = dtv*(Bst[1][s0+s]*xpv);
      y = fmaf(h[s], Cst[0][s0+s], y);
      Bprev[s] = Bst[1][s0+s];
    }
    const float ytot = y + __shfl_xor(y, 1, 64);
    if (sh == 0) ys[0][d] = (ytot + xpv*dvp)*__half2float(zsh[rowE]);
    xpm1 = xpv;
    tstart = 1;
  }
  for (int tt=tstart; tt<t0+TC; ++tt){
    const size_t rowE = (bL + tt)*DI + d;
    const float dtv = softplusf_(fmaf(dst[tt-t0], wdt, bdtv));
    const float xpv = __half2float(xph[rowE]);
    const float lamv = lst[tt - t0];
    const int j = tt - t0;
    const float dl = dtv*lamv;
    const float dml = dtv - dl;
    float y = 0.0f;
    #pragma unroll
    for (int s=0;s<8;s++){
      const float a = __expf(A[s]*dtv);
      const float Bc = Bst[j+1][s0+s];
      const float u = fmaf(dml*a, Bprev[s]*xpm1, dl*(Bc*xpv));
      h[s] = fmaf(a, h[s], u);
      y = fmaf(h[s], Cst[j][s0+s], y);
      Bprev[s] = Bc;
    }
    const float ytot = y + __shfl_xor(y, 1, 64);
    if (sh == 0) ys[j][d] = (ytot + xpv*dvp)*__half2float(zsh[rowE]);
    xpm1 = xpv;
  }
  __syncthreads();

  // out_proj (16 rows x 128 cols, K=256) + residual; 512 threads, 4 cols each
  {
    const int r  = t >> 5;
    const int cg = t & 31;
    const int c0 = cg*4;
    float acc[4] = {0.0f,0.0f,0.0f,0.0f};
    for (int k=0;k<DI;k+=4){
      const float4 yv = *(const float4*)&ys[r][k];
      const float yy[4] = {yv.x, yv.y, yv.z, yv.w};
      #pragma unroll
      for (int j=0;j<4;j++){
        const float4 wa = *(const float4*)&Wo[(size_t)(k+j)*DM + c0];
        acc[0]=fmaf(yy[j],wa.x,acc[0]); acc[1]=fmaf(yy[j],wa.y,acc[1]);
        acc[2]=fmaf(yy[j],wa.z,acc[2]); acc[3]=fmaf(yy[j],wa.w,acc[3]);
      }
    }
    const size_t row = bL + t0 + r;
    float4 h0 = *(const float4*)&hb[row*DM + c0];
    h0.x+=acc[0]; h0.y+=acc[1]; h0.z+=acc[2]; h0.w+=acc[3];
    *(float4*)&hb[row*DM + c0] = h0;
  }
}

// ---------------- final LN + landmark attention (one block per batch) ----------------
__global__ __launch_bounds__(256) void attn_kernel(
    const float* __restrict__ hb, const float* __restrict__ sk,
    const float* __restrict__ hw,
    const float* __restrict__ fnw, const float* __restrict__ fnb,
    const float* __restrict__ WQ, const float* __restrict__ bQ,
    const float* __restrict__ WK, const float* __restrict__ bK,
    const float* __restrict__ WV, const float* __restrict__ bV,
    const float* __restrict__ WO, const float* __restrict__ bO,
    float* __restrict__ outp)
{
  __shared__ float kv[KLM][DM+4];
  __shared__ float mo[DM];
  __shared__ float Qs[DM];
  __shared__ float qk[NHEAD][DM];
  __shared__ float bterm[NHEAD];
  __shared__ float sc[NHEAD][KLM];
  __shared__ float pbar[NHEAD][DM];
  __shared__ float attno[DM];
  __shared__ int idxl[KLM];
  __shared__ int redcnt[2][4];
  __shared__ int eqc[8][4], gtc[8][4];
  __shared__ float red_f[4];

  const int b = blockIdx.x;
  const int t = threadIdx.x;
  const int lane = t & 63, w = t >> 6;

  const float* hwp = hw + (size_t)b*SEQL;
  unsigned vb[8];
  #pragma unroll
  for (int q=0;q<8;q++) vb[q] = __float_as_uint(hwp[q*256 + t]);

  unsigned kth = 0u;
  for (int bit=31; bit>=0; --bit){
    const unsigned cand = kth | (1u << bit);
    int c0 = 0;
    #pragma unroll
    for (int q=0;q<8;q++) c0 += __popcll(__ballot(vb[q] >= cand));
    const int par = bit & 1;
    if (lane == 0) redcnt[par][w] = c0;
    __syncthreads();
    const int tot = redcnt[par][0]+redcnt[par][1]+redcnt[par][2]+redcnt[par][3];
    if (tot >= KLM) kth = cand;
  }

  unsigned long long beq[8], bgt[8];
  #pragma unroll
  for (int q=0;q<8;q++){
    beq[q] = __ballot(vb[q] == kth);
    bgt[q] = __ballot(vb[q] >  kth);
  }
  if (lane == 0){
    #pragma unroll
    for (int q=0;q<8;q++){ eqc[q][w] = __popcll(beq[q]); gtc[q][w] = __popcll(bgt[q]); }
  }
  __syncthreads();
  {
    int gtTot = 0;
    #pragma unroll
    for (int q=0;q<8;q++) gtTot += gtc[q][0]+gtc[q][1]+gtc[q][2]+gtc[q][3];
    const int need_eq = KLM - gtTot;
    const unsigned long long lmask = (lane==0) ? 0ull : ((~0ull) >> (64-lane));
    int eqPfx = 0, gtPfx = 0;
    #pragma unroll
    for (int q=0;q<8;q++){
      int eqWP = 0, gtWP = 0;
      for (int w2=0; w2<w; ++w2){ eqWP += eqc[q][w2]; gtWP += gtc[q][w2]; }
      const int eqBefore = eqPfx + eqWP + __popcll(beq[q] & lmask);
      const int gtBefore = gtPfx + gtWP + __popcll(bgt[q] & lmask);
      if (vb[q] > kth){
        const int pos = gtBefore + min(eqBefore, need_eq);
        if (pos < KLM) idxl[pos] = q*256 + t;
      } else if (vb[q] == kth && eqBefore < need_eq){
        const int pos = gtBefore + eqBefore;
        if (pos < KLM) idxl[pos] = q*256 + t;
      }
      eqPfx += eqc[q][0]+eqc[q][1]+eqc[q][2]+eqc[q][3];
      gtPfx += gtc[q][0]+gtc[q][1]+gtc[q][2]+gtc[q][3];
    }
  }
  __syncthreads();

  {
    const float* hr = hb + ((size_t)b*SEQL + (SEQL-1))*DM;
    const float hv = (t < DM) ? hr[t] : 0.0f;
    const float ssum = block_sum256(hv, red_f);
    const float mean = ssum*(1.0f/DM);
    const float dv = (t < DM) ? (hv - mean) : 0.0f;
    const float vsum = block_sum256(dv*dv, red_f);
    const float inv = 1.0f/sqrtf(vsum*(1.0f/DM) + 1e-5f);
    if (t < DM) mo[t] = dv*inv*fnw[t] + fnb[t];
  }
  __syncthreads();

  for (int e=t; e<KLM*DM; e+=256){
    const int j = e >> 7, cc = e & (DM-1);
    kv[j][cc] = sk[((size_t)b*SEQL + idxl[j])*DM + cc];
  }
  __syncthreads();

  if (t < DM){
    float a = bQ[t];
    #pragma unroll 4
    for (int k=0;k<DM;k++) a = fmaf(mo[k], WQ[(size_t)k*DM + t], a);
    Qs[t] = a;
  }
  __syncthreads();
  for (int e=t; e<NHEAD*DM; e+=256){
    const int hh = e >> 7, m = e & (DM-1);
    const int c0 = hh*DHEAD;
    float a = 0.0f;
    #pragma unroll
    for (int cc=0; cc<DHEAD; cc++) a = fmaf(WK[(size_t)m*DM + c0 + cc], Qs[c0+cc], a);
    qk[hh][m] = a;
  }
  if (t < NHEAD){
    float a = 0.0f;
    for (int cc=0; cc<DHEAD; cc++) a += bK[t*DHEAD+cc]*Qs[t*DHEAD+cc];
    bterm[t] = a;
  }
  __syncthreads();
  for (int e=t; e<NHEAD*KLM; e+=256){
    const int hh = e/KLM, j = e - hh*KLM;
    float a = bterm[hh];
    for (int m=0;m<DM;m+=4){
      const float4 kvv = *(const float4*)&kv[j][m];
      const float4 qv  = *(const float4*)&qk[hh][m];
      a = fmaf(kvv.x,qv.x,a); a = fmaf(kvv.y,qv.y,a);
      a = fmaf(kvv.z,qv.z,a); a = fmaf(kvv.w,qv.w,a);
    }
    sc[hh][j] = a*0.17677669529663687f;
  }
  __syncthreads();
  {
    const int hh = w;
    const float v0 = (lane < KLM) ? sc[hh][lane] : -3.0e38f;
    const float v1 = (lane+64 < KLM) ? sc[hh][lane+64] : -3.0e38f;
    float mx = fmaxf(v0, v1);
    #pragma unroll
    for (int o2=32;o2>0;o2>>=1) mx = fmaxf(mx, __shfl_xor(mx,o2,64));
    const float e0 = (lane < KLM) ? expf(v0-mx) : 0.0f;
    const float e1 = (lane+64 < KLM) ? expf(v1-mx) : 0.0f;
    float sm = e0+e1;
    #pragma unroll
    for (int o2=32;o2>0;o2>>=1) sm += __shfl_xor(sm,o2,64);
    const float inv2 = 1.0f/sm;
    if (lane < KLM) sc[hh][lane] = e0*inv2;
    if (lane+64 < KLM) sc[hh][lane+64] = e1*inv2;
  }
  __syncthreads();
  for (int e=t; e<NHEAD*DM; e+=256){
    const int hh = e >> 7, m = e & (DM-1);
    float a = 0.0f;
    #pragma unroll 4
    for (int j=0;j<KLM;j++) a = fmaf(sc[hh][j], kv[j][m], a);
    pbar[hh][m] = a;
  }
  __syncthreads();
  if (t < DM){
    const int hh = t >> 5;
    float a = bV[t];
    for (int m=0;m<DM;m+=4){
      const float4 pv = *(const float4*)&pbar[hh][m];
      a = fmaf(pv.x, WV[(size_t)(m+0)*DM + t], a);
      a = fmaf(pv.y, WV[(size_t)(m+1)*DM + t], a);
      a = fmaf(pv.z, WV[(size_t)(m+2)*DM + t], a);
      a = fmaf(pv.w, WV[(size_t)(m+3)*DM + t], a);
    }
    attno[t] = a;
  }
  __syncthreads();
  if (t < DM){
    float a = bO[t];
    #pragma unroll 4
    for (int c2=0;c2<DM;c2++) a = fmaf(attno[c2], WO[(size_t)c2*DM + t], a);
    outp[(size_t)b*DM + t] = a;
  }
}

extern "C" void kernel_launch(void* const* d_in, const int* in_sizes, int n_in,
                              void* d_out, int out_size, void* d_ws, size_t ws_size,
                              hipStream_t stream)
{
  (void)in_sizes; (void)n_in; (void)out_size; (void)ws_size;
  const float* x    = (const float*)d_in[0];
  const float* hw   = (const float*)d_in[1];
  const float* embW = (const float*)d_in[2];
  const float* embB = (const float*)d_in[3];
  const float* skW  = (const float*)d_in[4];
  const float* skB  = (const float*)d_in[5];
  const float* inW  = (const float*)d_in[6];
  const float* xpW  = (const float*)d_in[7];
  const float* dtW  = (const float*)d_in[8];
  const float* dtB  = (const float*)d_in[9];
  const float* Alog = (const float*)d_in[10];
  const float* Bb   = (const float*)d_in[11];
  const float* Cb   = (const float*)d_in[12];
  const float* Bnw  = (const float*)d_in[13];
  const float* Cnw  = (const float*)d_in[14];
  const float* rf   = (const float*)d_in[15];
  const float* Dpar = (const float*)d_in[16];
  const float* outW = (const float*)d_in[17];
  const float* lnW  = (const float*)d_in[18];
  const float* lnB  = (const float*)d_in[19];
  const float* fnW  = (const float*)d_in[20];
  const float* fnB  = (const float*)d_in[21];
  const float* WQ = (const float*)d_in[22]; const float* bQ = (const float*)d_in[23];
  const float* WK = (const float*)d_in[24]; const float* bK = (const float*)d_in[25];
  const float* WV = (const float*)d_in[26]; const float* bV = (const float*)d_in[27];
  const float* WO = (const float*)d_in[28]; const float* bO = (const float*)d_in[29];

  float* ws = (float*)d_ws;
  size_t off = 0;
  float* hb    = ws + off; off += (size_t)BSZ*SEQL*DM;
  float* sk    = ws + off; off += (size_t)BSZ*SEQL*DM;
  __half* xph  = (__half*)(ws + off); off += (size_t)BSZ*SEQL*DI/2;
  __half* zsh  = (__half*)(ws + off); off += (size_t)BSZ*SEQL*DI/2;
  float* Bmb   = ws + off; off += (size_t)BSZ*SEQL*DS;
  float* Cmb   = ws + off; off += (size_t)BSZ*SEQL*DS;
  float* lamb  = ws + off; off += (size_t)BSZ*SEQL;
  float* mdtb  = ws + off; off += (size_t)BSZ*SEQL;
  float* dtin  = ws + off; off += (size_t)BSZ*SEQL;
  float* Shalf = ws + off; off += (size_t)BSZ*(SEQL/NROWS)*DI;
  float* hend  = ws + off; off += (size_t)BSZ*NC*DI*DS;
  float2* cst  = (float2*)(ws + off);                    // BSZ*SEQL*8 float2

  embed_kernel<<<BSZ*SEQL/EROWS, 256, 0, stream>>>(x, hw, embW, embB, skW, skB, hb, sk);

  for (int i=0;i<NL;i++){
    pre_kernel<<<BSZ*SEQL/NROWS, 256, 0, stream>>>(hb,
        inW + (size_t)i*DM*2*DI, xpW + (size_t)i*DI*34,
        dtW + (size_t)i*DI, dtB + (size_t)i*DI,
        Bb + i*DS, Cb + i*DS, Bnw + i*DS, Cnw + i*DS,
        lnW + i*DM, lnB + i*DM,
        xph, zsh, dtin, Shalf, Bmb, Cmb, lamb, mdtb);
    cumsum_cs_kernel<<<BSZ, 256, 0, stream>>>(mdtb, rf + i*8, cst);
    scan1_kernel<<<BSZ*NC, 512, 0, stream>>>(xph, dtin,
        dtW + (size_t)i*DI, dtB + (size_t)i*DI,
        Bmb, lamb, cst, Alog + (size_t)i*DI*DS, hend);
    scan2_kernel<<<BSZ*DI, 128, 0, stream>>>(hend, Shalf, Alog + (size_t)i*DI*DS);
    scan3post_kernel<<<BSZ*NC, 512, 0, stream>>>(xph, dtin,
        dtW + (size_t)i*DI, dtB + (size_t)i*DI,
        Bmb, Cmb, lamb, zsh, cst,
        Alog + (size_t)i*DI*DS, Dpar + (size_t)i*DI, hend,
        outW + (size_t)i*DI*DM, hb);
  }

  attn_kernel<<<BSZ, 256, 0, stream>>>(hb, sk, hw, fnW, fnB,
      WQ, bQ, WK, bK, WV, bV, WO, bO, (float*)d_out);
}

// Round 7
// 576.339 us; speedup vs baseline: 1.4327x; 1.1375x over previous
//
#include <hip/hip_runtime.h>
#include <hip/hip_fp16.h>
#include <math.h>

#define BSZ   4
#define SEQL  2048
#define DIN   40
#define DM    128
#define DI    256
#define DS    16
#define NL    4
#define NHEAD 4
#define DHEAD 32
#define KLM   100
#define NC    128       // chunks per sequence
#define TC    16        // SEQL / NC
#define NROWS 8         // rows per pre block
#define EROWS 16

__device__ __forceinline__ float rcp_(float x){ return __builtin_amdgcn_rcpf(x); }
__device__ __forceinline__ float sigmoidf_(float x){ return rcp_(1.0f + __expf(-x)); }
__device__ __forceinline__ float siluf_(float x){ return x*rcp_(1.0f + __expf(-x)); }
__device__ __forceinline__ float softplusf_(float x){ return fmaxf(x,0.0f) + __logf(1.0f + __expf(-fabsf(x))); }

__device__ __forceinline__ float block_sum256(float v, float* red){
  #pragma unroll
  for (int o=32;o>0;o>>=1) v += __shfl_down(v,o,64);
  __syncthreads();
  if ((threadIdx.x & 63)==0) red[threadIdx.x>>6] = v;
  __syncthreads();
  return red[0]+red[1]+red[2]+red[3];
}
__device__ __forceinline__ void load8(const float* p, float* r){
  const float4* q = (const float4*)p;
  float4 a=q[0], b=q[1];
  r[0]=a.x;r[1]=a.y;r[2]=a.z;r[3]=a.w; r[4]=b.x;r[5]=b.y;r[6]=b.z;r[7]=b.w;
}
__device__ __forceinline__ void store8(float* p, const float* r){
  float4* q = (float4*)p;
  q[0]=make_float4(r[0],r[1],r[2],r[3]);  q[1]=make_float4(r[4],r[5],r[6],r[7]);
}
__device__ __forceinline__ void load16(const float* p, float* r){
  load8(p, r); load8(p+8, r+8);
}
__device__ __forceinline__ void store16(float* p, const float* r){
  store8(p, r); store8(p+8, r+8);
}

// ---------------- embed: 16 rows/block ----------------
__global__ __launch_bounds__(256) void embed_kernel(
    const float* __restrict__ x, const float* __restrict__ hw,
    const float* __restrict__ eW, const float* __restrict__ eb,
    const float* __restrict__ sW, const float* __restrict__ sb,
    float* __restrict__ hb, float* __restrict__ sk)
{
  __shared__ float xr[EROWS][DIN];
  const int t = threadIdx.x;
  const size_t R0 = (size_t)blockIdx.x * EROWS;
  for (int e=t; e<EROWS*DIN; e+=256) ((float*)xr)[e] = x[R0*DIN + e];
  __syncthreads();
  const int c = t & (DM-1), g = t >> 7;
  float ae[8], as[8];
  #pragma unroll
  for (int j=0;j<8;j++){ ae[j]=0.0f; as[j]=0.0f; }
  for (int k=0;k<DIN;k++){
    const float we  = eW[(size_t)k*DM + c];
    const float ws_ = sW[(size_t)k*DM + c];
    #pragma unroll
    for (int j=0;j<8;j++){
      const float xv = xr[g*8+j][k];
      ae[j] = fmaf(xv, we, ae[j]);
      as[j] = fmaf(xv, ws_, as[j]);
    }
  }
  const float ebv = eb[c], sbv = sb[c];
  #pragma unroll
  for (int j=0;j<8;j++){
    const size_t R = R0 + g*8 + j;
    const float w = hw[R];
    hb[R*DM + c] = (ae[j]+ebv)*w;
    sk[R*DM + c] = (as[j]+sbv)*w;
  }
}

// ---------------- fused pre: LN -> in_proj -> silu -> x_proj -> B/C/dt/lam ----------------
__global__ __launch_bounds__(256) void pre_kernel(
    const float* __restrict__ hb,
    const float* __restrict__ Wi, const float* __restrict__ Wx,
    const float* __restrict__ Wdt, const float* __restrict__ bdt,
    const float* __restrict__ Bb, const float* __restrict__ Cb,
    const float* __restrict__ Bnw, const float* __restrict__ Cnw,
    const float* __restrict__ lnw, const float* __restrict__ lnb,
    __half* __restrict__ xph, __half* __restrict__ zsh,
    float* __restrict__ dtin, float* __restrict__ Shalf,
    float* __restrict__ Bmb, float* __restrict__ Cmb,
    float* __restrict__ lamb, float* __restrict__ mdtb)
{
  __shared__ float xin[NROWS][DM+4];
  __shared__ float xps[NROWS][DI+4];
  __shared__ float spl[NROWS][40];
  __shared__ float pr[NROWS][4];

  const int t = threadIdx.x;
  const size_t R0 = (size_t)blockIdx.x * NROWS;

  { // LayerNorm: 32 threads per row
    const int r = t >> 5, j = t & 31;
    const float4 v = ((const float4*)(hb + (R0 + r)*DM))[j];
    float s = v.x+v.y+v.z+v.w;
    #pragma unroll
    for (int o=16;o>0;o>>=1) s += __shfl_xor(s,o,32);
    const float m = s*(1.0f/DM);
    const float dx=v.x-m, dy=v.y-m, dz=v.z-m, dw=v.w-m;
    float ss = dx*dx+dy*dy+dz*dz+dw*dw;
    #pragma unroll
    for (int o=16;o>0;o>>=1) ss += __shfl_xor(ss,o,32);
    const float inv = 1.0f/sqrtf(ss*(1.0f/DM) + 1e-5f);
    const int c = j*4;
    xin[r][c+0] = dx*inv*lnw[c+0] + lnb[c+0];
    xin[r][c+1] = dy*inv*lnw[c+1] + lnb[c+1];
    xin[r][c+2] = dz*inv*lnw[c+2] + lnb[c+2];
    xin[r][c+3] = dw*inv*lnw[c+3] + lnb[c+3];
  }
  __syncthreads();

  { // xz = xin @ Wi; thread t owns cols 2t, 2t+1
    float2 a[NROWS];
    #pragma unroll
    for (int r=0;r<NROWS;r++){ a[r].x=0.0f; a[r].y=0.0f; }
    for (int k=0;k<DM;k+=4){
      const float2 w0 = *(const float2*)&Wi[(size_t)(k+0)*(2*DI) + 2*t];
      const float2 w1 = *(const float2*)&Wi[(size_t)(k+1)*(2*DI) + 2*t];
      const float2 w2 = *(const float2*)&Wi[(size_t)(k+2)*(2*DI) + 2*t];
      const float2 w3 = *(const float2*)&Wi[(size_t)(k+3)*(2*DI) + 2*t];
      #pragma unroll
      for (int r=0;r<NROWS;r++){
        const float4 xv = *(const float4*)&xin[r][k];
        a[r].x = fmaf(xv.x,w0.x,a[r].x); a[r].y = fmaf(xv.x,w0.y,a[r].y);
        a[r].x = fmaf(xv.y,w1.x,a[r].x); a[r].y = fmaf(xv.y,w1.y,a[r].y);
        a[r].x = fmaf(xv.z,w2.x,a[r].x); a[r].y = fmaf(xv.z,w2.y,a[r].y);
        a[r].x = fmaf(xv.w,w3.x,a[r].x); a[r].y = fmaf(xv.w,w3.y,a[r].y);
      }
    }
    if (t < 128){
      #pragma unroll
      for (int r=0;r<NROWS;r++){
        const float sx = siluf_(a[r].x), sy = siluf_(a[r].y);
        xps[r][2*t] = sx; xps[r][2*t+1] = sy;
        *(__half2*)&xph[(R0+r)*DI + 2*t] =
            __halves2half2(__float2half_rn(sx), __float2half_rn(sy));
      }
    } else {
      const int zc = 2*t - 2*DI + DI;
      #pragma unroll
      for (int r=0;r<NROWS;r++){
        const float sx = siluf_(a[r].x), sy = siluf_(a[r].y);
        *(__half2*)&zsh[(R0+r)*DI + zc] =
            __halves2half2(__float2half_rn(sx), __float2half_rn(sy));
      }
    }
  }
  __syncthreads();

  // sp = xp @ Wx.  136 tasks = 8 rows x 17 col-pairs
  if (t < 136){
    const int r = t & 7, op = t >> 3;
    float ax=0.0f, ay=0.0f;
    for (int k=0;k<DI;k+=4){
      const float4 xv = *(const float4*)&xps[r][k];
      const float2 w0 = *(const float2*)&Wx[(size_t)(k+0)*34 + 2*op];
      const float2 w1 = *(const float2*)&Wx[(size_t)(k+1)*34 + 2*op];
      const float2 w2 = *(const float2*)&Wx[(size_t)(k+2)*34 + 2*op];
      const float2 w3 = *(const float2*)&Wx[(size_t)(k+3)*34 + 2*op];
      ax = fmaf(xv.x,w0.x,ax); ay = fmaf(xv.x,w0.y,ay);
      ax = fmaf(xv.y,w1.x,ax); ay = fmaf(xv.y,w1.y,ay);
      ax = fmaf(xv.z,w2.x,ax); ay = fmaf(xv.z,w2.y,ay);
      ax = fmaf(xv.w,w3.x,ax); ay = fmaf(xv.w,w3.y,ay);
    }
    spl[r][2*op] = ax; spl[r][2*op+1] = ay;
  }
  __syncthreads();

  { // B/C rms-norm: 256 tasks = 2 halves x 8 rows x 16 states
    const int half = t >> 7;
    const int r2 = (t >> 4) & 7, s2 = t & 15;
    const float* bias = half ? Cb : Bb;
    const float* wn   = half ? Cnw : Bnw;
    const float v = spl[r2][half*DS + s2] + bias[s2];
    float ss = v*v;
    #pragma unroll
    for (int o=8;o>0;o>>=1) ss += __shfl_xor(ss,o,16);
    const float inv = 1.0f/sqrtf(ss*(1.0f/DS) + 1.1920929e-07f);
    (half ? Cmb : Bmb)[(R0+r2)*DS + s2] = v*inv*wn[s2];
  }

  { // dt: thread = d; loop 8 rows; accumulate half-chunk sum
    const int lane = t & 63, w = t >> 6;
    const float wdt = Wdt[t], bdtv = bdt[t];
    float Sd = 0.0f;
    #pragma unroll
    for (int r=0;r<NROWS;r++){
      const float dval = softplusf_(fmaf(spl[r][32], wdt, bdtv));
      Sd += dval;
      float s = dval;
      #pragma unroll
      for (int o=32;o>0;o>>=1) s += __shfl_xor(s,o,64);
      if (lane==0) pr[r][w] = s;
    }
    Shalf[(size_t)blockIdx.x * DI + t] = Sd;
    if (t < NROWS){
      lamb[R0+t] = sigmoidf_(spl[t][33]);
      dtin[R0+t] = spl[t][32];
    }
  }
  __syncthreads();
  if (t < NROWS)
    mdtb[R0+t] = (pr[t][0]+pr[t][1]+pr[t][2]+pr[t][3])*(1.0f/DI);
}

// ---------------- cumsum (f64) -> global ----------------
__global__ __launch_bounds__(256) void cumsum_kernel(
    const float* __restrict__ mdt, double* __restrict__ csum_g)
{
  __shared__ double wsum[4];
  const int b = blockIdx.x, t = threadIdx.x;
  const int lane = t & 63, w = t >> 6;
  const float* p = mdt + (size_t)b*SEQL + (size_t)t*8;
  double v[8]; double s = 0.0;
  #pragma unroll
  for (int q=0;q<8;q++){ v[q] = (double)p[q]; s += v[q]; }
  double sc = s;
  #pragma unroll
  for (int o=1;o<64;o<<=1){
    const double nb = __shfl_up(sc, o, 64);
    if (lane >= o) sc += nb;
  }
  if (lane==63) wsum[w] = sc;
  __syncthreads();
  double woff = 0.0;
  for (int j=0;j<w;j++) woff += wsum[j];
  double run = woff + sc - s;
  double* dst = csum_g + (size_t)b*SEQL + (size_t)t*8;
  #pragma unroll
  for (int q=0;q<8;q++){ run += v[q]; dst[q] = run; }
}

// ---------------- cos/sin fill (parallel, 32 blocks) ----------------
__global__ __launch_bounds__(256) void csfill_kernel(
    const double* __restrict__ csum_g, const float* __restrict__ rf,
    float2* __restrict__ cst)
{
  __shared__ double fqs[8];
  const int t = threadIdx.x;
  if (t < 8){
    const double xfr = (double)rf[t];
    fqs[t] = fmax(xfr, 0.0) + log1p(exp(-fabs(xfr)));
  }
  __syncthreads();
  const int row = blockIdx.x*256 + t;    // BSZ*SEQL rows
  const double ab = csum_g[row];
  const double TWO_PI = 6.283185307179586;
  const double INV2PI = 0.15915494309189535;
  float2 o8[8];
  #pragma unroll
  for (int f=0; f<8; f++){
    const double ang = ab * fqs[f];
    const double red = ang - floor(ang*INV2PI)*TWO_PI;
    float sa, ca;
    __sincosf((float)red, &sa, &ca);
    o8[f] = make_float2(ca, sa);
  }
  float4* dst = (float4*)&cst[(size_t)row*8];
  dst[0] = make_float4(o8[0].x,o8[0].y,o8[1].x,o8[1].y);
  dst[1] = make_float4(o8[2].x,o8[2].y,o8[3].x,o8[3].y);
  dst[2] = make_float4(o8[4].x,o8[4].y,o8[5].x,o8[5].y);
  dst[3] = make_float4(o8[6].x,o8[6].y,o8[7].x,o8[7].y);
}

// ---------------- scan phase 1 (s-split, 512 threads; xp staged in LDS) ----------------
__global__ __launch_bounds__(512) void scan1_kernel(
    const __half* __restrict__ xph, const float* __restrict__ dtin,
    const float* __restrict__ Wdt, const float* __restrict__ bdt,
    const float* __restrict__ Bmb, const float* __restrict__ lamb,
    const float2* __restrict__ cst,
    const float* __restrict__ Alog, float* __restrict__ hend)
{
  __shared__ float Bst[TC+1][DS];
  __shared__ float lst[TC];
  __shared__ float dsl[TC];
  __shared__ __half xpl[TC+1][DI+8];
  const int t = threadIdx.x;
  const int d  = t >> 1;
  const int s0 = (t & 1) * 8;
  const int c = blockIdx.x & (NC-1);
  const int b = blockIdx.x >> 7;
  const size_t bL = (size_t)b*SEQL;
  const int t0 = c*TC;
  const int id = blockIdx.x*256 + d;

  for (int e=t; e<(TC+1)*DS; e+=512){
    const int j = e >> 4, s = e & 15;
    const int trow = t0 - 1 + j;
    Bst[j][s] = (trow >= 0) ? Bmb[(bL + trow)*DS + s] : 0.0f;
  }
  for (int e=t; e<(TC+1)*DI; e+=512){
    const int j = e >> 8, dd = e & (DI-1);
    const int trow = t0 - 1 + j;
    xpl[j][dd] = (trow >= 0) ? xph[(bL + trow)*DI + dd] : __float2half_rn(0.0f);
  }
  if (t < TC){
    lst[t] = lamb[bL + t0 + t];
    dsl[t] = dtin[bL + t0 + t];
  }
  __syncthreads();
  if (t < 136){
    const int j = t >> 3, f = t & 7;
    const int trow = t0 - 1 + j;
    if (trow >= 0){
      const float2 cs = cst[((size_t)(bL + trow))*8 + f];
      const float e0 = Bst[j][2*f], o0 = Bst[j][2*f+1];
      Bst[j][2*f]   = e0*cs.x - o0*cs.y;
      Bst[j][2*f+1] = e0*cs.y + o0*cs.x;
    }
  }
  __syncthreads();

  float A[8];
  #pragma unroll
  for (int s=0;s<8;s++) A[s] = fminf(-__expf(Alog[d*DS + s0 + s]), -1e-4f);
  const float wdt = Wdt[d], bdtv = bdt[d];
  float h[8], Bprev[8];
  #pragma unroll
  for (int s=0;s<8;s++) h[s]=0.0f;
  float xpm1;
  int tstart;
  if (t0 > 0){
    #pragma unroll
    for (int s=0;s<8;s++) Bprev[s] = Bst[0][s0+s];
    xpm1 = __half2float(xpl[0][d]);
    tstart = t0;
  } else {
    const float dtv = softplusf_(fmaf(dsl[0], wdt, bdtv));
    const float xpv = __half2float(xpl[1][d]);
    #pragma unroll
    for (int s=0;s<8;s++){
      h[s] = dtv*(Bst[1][s0+s]*xpv);
      Bprev[s] = Bst[1][s0+s];
    }
    xpm1 = xpv;
    tstart = 1;
  }
  for (int tt=tstart; tt<t0+TC; ++tt){
    const int j = tt - t0;
    const float dtv = softplusf_(fmaf(dsl[j], wdt, bdtv));
    const float xpv = __half2float(xpl[j+1][d]);
    const float lamv = lst[j];
    const float dl = dtv*lamv;
    const float dml = dtv - dl;
    #pragma unroll
    for (int s=0;s<8;s++){
      const float a = __expf(A[s]*dtv);
      const float Bc = Bst[j+1][s0+s];
      const float u = fmaf(dml*a, Bprev[s]*xpm1, dl*(Bc*xpv));
      h[s] = fmaf(a, h[s], u);
      Bprev[s] = Bc;
    }
    xpm1 = xpv;
  }
  store8(hend + (size_t)id*DS + s0, h);
}

// ---------------- scan phase 2: parallel Kogge-Stone over chunks; P = exp(A*S) ----------------
__global__ __launch_bounds__(128) void scan2_kernel(
    float* __restrict__ hend, const float* __restrict__ Shalf,
    const float* __restrict__ Alog)
{
  __shared__ float hS[NC][DS+1];
  __shared__ float pS[NC][DS+1];
  const int c = threadIdx.x;
  const int d = blockIdx.x & (DI-1);
  const int b = blockIdx.x >> 8;
  const float S = Shalf[(size_t)(b*(SEQL/NROWS) + 2*c)*DI + d]
                + Shalf[(size_t)(b*(SEQL/NROWS) + 2*c + 1)*DI + d];
  float P[DS], h[DS];
  #pragma unroll
  for (int s=0;s<DS;s++){
    const float A = fminf(-__expf(Alog[d*DS+s]), -1e-4f);
    P[s] = __expf(A*S);
  }
  load16(hend + (((size_t)(b*NC + c))*DI + d)*DS, h);
  #pragma unroll
  for (int s=0;s<DS;s++){ hS[c][s]=h[s]; pS[c][s]=P[s]; }
  __syncthreads();
  for (int off=1; off<NC; off<<=1){
    float hn[DS], pn[DS];
    const int src = c - off;
    if (src >= 0){
      #pragma unroll
      for (int s=0;s<DS;s++){ hn[s]=hS[src][s]; pn[s]=pS[src][s]; }
    }
    __syncthreads();
    if (src >= 0){
      #pragma unroll
      for (int s=0;s<DS;s++){
        h[s] = fmaf(P[s], hn[s], h[s]);
        P[s] *= pn[s];
        hS[c][s] = h[s]; pS[c][s] = P[s];
      }
    }
    __syncthreads();
  }
  float o[DS];
  if (c == 0){
    #pragma unroll
    for (int s=0;s<DS;s++) o[s] = 0.0f;
  } else {
    #pragma unroll
    for (int s=0;s<DS;s++) o[s] = hS[c-1][s];
  }
  store16(hend + (((size_t)(b*NC + c))*DI + d)*DS, o);
}

// ---------------- scan phase 3 + out_proj + residual (s-split; xp/zs staged) ----------------
__global__ __launch_bounds__(512) void scan3post_kernel(
    const __half* __restrict__ xph, const float* __restrict__ dtin,
    const float* __restrict__ Wdt, const float* __restrict__ bdt,
    const float* __restrict__ Bmb, const float* __restrict__ Cmb,
    const float* __restrict__ lamb, const __half* __restrict__ zsh,
    const float2* __restrict__ cst,
    const float* __restrict__ Alog, const float* __restrict__ Dv,
    const float* __restrict__ Hin, const float* __restrict__ Wo,
    float* __restrict__ hb)
{
  __shared__ float Bst[TC+1][DS];
  __shared__ float Cst[TC][DS];
  __shared__ float lst[TC];
  __shared__ float dsl[TC];
  __shared__ __half xpl[TC+1][DI+8];
  __shared__ __half zsl[TC][DI+8];
  __shared__ float ys[TC][DI+4];
  const int t = threadIdx.x;
  const int d  = t >> 1;
  const int sh = t & 1;
  const int s0 = sh * 8;
  const int c = blockIdx.x & (NC-1);
  const int b = blockIdx.x >> 7;
  const size_t bL = (size_t)b*SEQL;
  const int t0 = c*TC;
  const int id = blockIdx.x*256 + d;

  for (int e=t; e<(TC+1)*DS; e+=512){
    const int j = e >> 4, s = e & 15;
    const int trow = t0 - 1 + j;
    Bst[j][s] = (trow >= 0) ? Bmb[(bL + trow)*DS + s] : 0.0f;
    if (j < TC) Cst[j][s] = Cmb[(bL + t0 + j)*DS + s];
  }
  for (int e=t; e<(TC+1)*DI; e+=512){
    const int j = e >> 8, dd = e & (DI-1);
    const int trow = t0 - 1 + j;
    xpl[j][dd] = (trow >= 0) ? xph[(bL + trow)*DI + dd] : __float2half_rn(0.0f);
    if (j < TC) zsl[j][dd] = zsh[(bL + t0 + j)*DI + dd];
  }
  if (t < TC){
    lst[t] = lamb[bL + t0 + t];
    dsl[t] = dtin[bL + t0 + t];
  }
  __syncthreads();
  if (t < 264){
    if (t < 136){
      const int j = t >> 3, f = t & 7;
      const int trow = t0 - 1 + j;
      if (trow >= 0){
        const float2 cs = cst[((size_t)(bL + trow))*8 + f];
        const float e0 = Bst[j][2*f], o0 = Bst[j][2*f+1];
        Bst[j][2*f]   = e0*cs.x - o0*cs.y;
        Bst[j][2*f+1] = e0*cs.y + o0*cs.x;
      }
    } else {
      const int e2 = t - 136;
      const int j = e2 >> 3, f = e2 & 7;
      const float2 cs = cst[((size_t)(bL + t0 + j))*8 + f];
      const float e0 = Cst[j][2*f], o0 = Cst[j][2*f+1];
      Cst[j][2*f]   = e0*cs.x - o0*cs.y;
      Cst[j][2*f+1] = e0*cs.y + o0*cs.x;
    }
  }
  __syncthreads();

  float A[8];
  #pragma unroll
  for (int s=0;s<8;s++) A[s] = fminf(-__expf(Alog[d*DS + s0 + s]), -1e-4f);
  const float wdt = Wdt[d], bdtv = bdt[d];
  const float dvp = Dv[d];
  float h[8], Bprev[8];
  load8(Hin + (size_t)id*DS + s0, h);
  float xpm1;
  int tstart;
  if (t0 > 0){
    #pragma unroll
    for (int s=0;s<8;s++) Bprev[s] = Bst[0][s0+s];
    xpm1 = __half2float(xpl[0][d]);
    tstart = t0;
  } else {
    const float dtv = softplusf_(fmaf(dsl[0], wdt, bdtv));
    const float xpv = __half2float(xpl[1][d]);
    float y = 0.0f;
    #pragma unroll
    for (int s=0;s<8;s++){
      h[s] = dtv*(Bst[1][s0+s]*xpv);
      y = fmaf(h[s], Cst[0][s0+s], y);
      Bprev[s] = Bst[1][s0+s];
    }
    const float ytot = y + __shfl_xor(y, 1, 64);
    if (sh == 0) ys[0][d] = (ytot + xpv*dvp)*__half2float(zsl[0][d]);
    xpm1 = xpv;
    tstart = 1;
  }
  for (int tt=tstart; tt<t0+TC; ++tt){
    const int j = tt - t0;
    const float dtv = softplusf_(fmaf(dsl[j], wdt, bdtv));
    const float xpv = __half2float(xpl[j+1][d]);
    const float lamv = lst[j];
    const float dl = dtv*lamv;
    const float dml = dtv - dl;
    float y = 0.0f;
    #pragma unroll
    for (int s=0;s<8;s++){
      const float a = __expf(A[s]*dtv);
      const float Bc = Bst[j+1][s0+s];
      const float u = fmaf(dml*a, Bprev[s]*xpm1, dl*(Bc*xpv));
      h[s] = fmaf(a, h[s], u);
      y = fmaf(h[s], Cst[j][s0+s], y);
      Bprev[s] = Bc;
    }
    const float ytot = y + __shfl_xor(y, 1, 64);
    if (sh == 0) ys[j][d] = (ytot + xpv*dvp)*__half2float(zsl[j][d]);
    xpm1 = xpv;
  }
  __syncthreads();

  // out_proj (16 rows x 128 cols, K=256) + residual; 512 threads, 4 cols each
  {
    const int r  = t >> 5;
    const int cg = t & 31;
    const int c0 = cg*4;
    float acc[4] = {0.0f,0.0f,0.0f,0.0f};
    for (int k=0;k<DI;k+=4){
      const float4 yv = *(const float4*)&ys[r][k];
      const float yy[4] = {yv.x, yv.y, yv.z, yv.w};
      #pragma unroll
      for (int j=0;j<4;j++){
        const float4 wa = *(const float4*)&Wo[(size_t)(k+j)*DM + c0];
        acc[0]=fmaf(yy[j],wa.x,acc[0]); acc[1]=fmaf(yy[j],wa.y,acc[1]);
        acc[2]=fmaf(yy[j],wa.z,acc[2]); acc[3]=fmaf(yy[j],wa.w,acc[3]);
      }
    }
    const size_t row = bL + t0 + r;
    float4 h0 = *(const float4*)&hb[row*DM + c0];
    h0.x+=acc[0]; h0.y+=acc[1]; h0.z+=acc[2]; h0.w+=acc[3];
    *(float4*)&hb[row*DM + c0] = h0;
  }
}

// ---------------- topk + final LN (4 blocks) ----------------
__global__ __launch_bounds__(256) void topk_kernel(
    const float* __restrict__ hb, const float* __restrict__ hw,
    const float* __restrict__ fnw, const float* __restrict__ fnb,
    int* __restrict__ idxl_g, float* __restrict__ mog)
{
  __shared__ int redcnt[2][4];
  __shared__ int eqc[8][4], gtc[8][4];
  __shared__ float red_f[4];

  const int b = blockIdx.x;
  const int t = threadIdx.x;
  const int lane = t & 63, w = t >> 6;

  const float* hwp = hw + (size_t)b*SEQL;
  unsigned vb[8];
  #pragma unroll
  for (int q=0;q<8;q++) vb[q] = __float_as_uint(hwp[q*256 + t]);

  unsigned kth = 0u;
  for (int bit=31; bit>=0; --bit){
    const unsigned cand = kth | (1u << bit);
    int c0 = 0;
    #pragma unroll
    for (int q=0;q<8;q++) c0 += __popcll(__ballot(vb[q] >= cand));
    const int par = bit & 1;
    if (lane == 0) redcnt[par][w] = c0;
    __syncthreads();
    const int tot = redcnt[par][0]+redcnt[par][1]+redcnt[par][2]+redcnt[par][3];
    if (tot >= KLM) kth = cand;
  }

  unsigned long long beq[8], bgt[8];
  #pragma unroll
  for (int q=0;q<8;q++){
    beq[q] = __ballot(vb[q] == kth);
    bgt[q] = __ballot(vb[q] >  kth);
  }
  if (lane == 0){
    #pragma unroll
    for (int q=0;q<8;q++){ eqc[q][w] = __popcll(beq[q]); gtc[q][w] = __popcll(bgt[q]); }
  }
  __syncthreads();
  {
    int gtTot = 0;
    #pragma unroll
    for (int q=0;q<8;q++) gtTot += gtc[q][0]+gtc[q][1]+gtc[q][2]+gtc[q][3];
    const int need_eq = KLM - gtTot;
    const unsigned long long lmask = (lane==0) ? 0ull : ((~0ull) >> (64-lane));
    int eqPfx = 0, gtPfx = 0;
    #pragma unroll
    for (int q=0;q<8;q++){
      int eqWP = 0, gtWP = 0;
      for (int w2=0; w2<w; ++w2){ eqWP += eqc[q][w2]; gtWP += gtc[q][w2]; }
      const int eqBefore = eqPfx + eqWP + __popcll(beq[q] & lmask);
      const int gtBefore = gtPfx + gtWP + __popcll(bgt[q] & lmask);
      if (vb[q] > kth){
        const int pos = gtBefore + min(eqBefore, need_eq);
        if (pos < KLM) idxl_g[b*KLM + pos] = q*256 + t;
      } else if (vb[q] == kth && eqBefore < need_eq){
        const int pos = gtBefore + eqBefore;
        if (pos < KLM) idxl_g[b*KLM + pos] = q*256 + t;
      }
      eqPfx += eqc[q][0]+eqc[q][1]+eqc[q][2]+eqc[q][3];
      gtPfx += gtc[q][0]+gtc[q][1]+gtc[q][2]+gtc[q][3];
    }
  }

  {
    const float* hr = hb + ((size_t)b*SEQL + (SEQL-1))*DM;
    const float hv = (t < DM) ? hr[t] : 0.0f;
    const float ssum = block_sum256(hv, red_f);
    const float mean = ssum*(1.0f/DM);
    const float dv = (t < DM) ? (hv - mean) : 0.0f;
    const float vsum = block_sum256(dv*dv, red_f);
    const float inv = 1.0f/sqrtf(vsum*(1.0f/DM) + 1e-5f);
    if (t < DM) mog[b*DM + t] = dv*inv*fnw[t] + fnb[t];
  }
}

// ---------------- per-(b,head) attention (16 blocks) ----------------
__global__ __launch_bounds__(256) void attnmid_kernel(
    const float* __restrict__ sk, const int* __restrict__ idxl_g,
    const float* __restrict__ mog,
    const float* __restrict__ WQ, const float* __restrict__ bQ,
    const float* __restrict__ WK, const float* __restrict__ bK,
    const float* __restrict__ WV, const float* __restrict__ bV,
    float* __restrict__ attnog)
{
  __shared__ float kv[KLM][DM+4];
  __shared__ float Qs[DHEAD];
  __shared__ float qk[DM];
  __shared__ float sc[KLM];
  __shared__ float pbar[DM];
  __shared__ float bterm_s;
  const int t = threadIdx.x;
  const int b = blockIdx.x >> 2, hh = blockIdx.x & 3;
  const int c0 = hh*DHEAD;

  for (int e=t; e<KLM*DM; e+=256){
    const int j = e >> 7, cc = e & (DM-1);
    kv[j][cc] = sk[((size_t)b*SEQL + idxl_g[b*KLM + j])*DM + cc];
  }
  if (t < DHEAD){
    float a = bQ[c0+t];
    #pragma unroll 4
    for (int k=0;k<DM;k++) a = fmaf(mog[b*DM+k], WQ[(size_t)k*DM + c0+t], a);
    Qs[t] = a;
  }
  __syncthreads();
  if (t < DM){
    float a = 0.0f;
    #pragma unroll
    for (int cc=0; cc<DHEAD; cc++) a = fmaf(WK[(size_t)t*DM + c0 + cc], Qs[cc], a);
    qk[t] = a;
  } else if (t == DM){
    float a = 0.0f;
    for (int cc=0; cc<DHEAD; cc++) a += bK[c0+cc]*Qs[cc];
    bterm_s = a;
  }
  __syncthreads();
  if (t < KLM){
    float a = bterm_s;
    for (int m=0;m<DM;m+=4){
      const float4 kvv = *(const float4*)&kv[t][m];
      const float4 qv  = *(const float4*)&qk[m];
      a = fmaf(kvv.x,qv.x,a); a = fmaf(kvv.y,qv.y,a);
      a = fmaf(kvv.z,qv.z,a); a = fmaf(kvv.w,qv.w,a);
    }
    sc[t] = a*0.17677669529663687f;
  }
  __syncthreads();
  if (t < 64){
    const int lane = t;
    const float v0 = (lane < KLM) ? sc[lane] : -3.0e38f;
    const float v1 = (lane+64 < KLM) ? sc[lane+64] : -3.0e38f;
    float mx = fmaxf(v0, v1);
    #pragma unroll
    for (int o2=32;o2>0;o2>>=1) mx = fmaxf(mx, __shfl_xor(mx,o2,64));
    const float e0 = (lane < KLM) ? __expf(v0-mx) : 0.0f;
    const float e1 = (lane+64 < KLM) ? __expf(v1-mx) : 0.0f;
    float sm = e0+e1;
    #pragma unroll
    for (int o2=32;o2>0;o2>>=1) sm += __shfl_xor(sm,o2,64);
    const float inv2 = rcp_(sm);
    if (lane < KLM) sc[lane] = e0*inv2;
    if (lane+64 < KLM) sc[lane+64] = e1*inv2;
  }
  __syncthreads();
  if (t < DM){
    float a = 0.0f;
    #pragma unroll 4
    for (int j=0;j<KLM;j++) a = fmaf(sc[j], kv[j][t], a);
    pbar[t] = a;
  }
  __syncthreads();
  if (t < DHEAD){
    const int cc = c0 + t;
    float a = bV[cc];
    #pragma unroll 4
    for (int m=0;m<DM;m++) a = fmaf(pbar[m], WV[(size_t)m*DM + cc], a);
    attnog[b*DM + cc] = a;
  }
}

// ---------------- output projection (4 blocks) ----------------
__global__ __launch_bounds__(128) void attnout_kernel(
    const float* __restrict__ attnog, const float* __restrict__ WO,
    const float* __restrict__ bO, float* __restrict__ outp)
{
  __shared__ float ao[DM];
  const int b = blockIdx.x, t = threadIdx.x;
  ao[t] = attnog[b*DM + t];
  __syncthreads();
  float a = bO[t];
  #pragma unroll 4
  for (int c2=0;c2<DM;c2++) a = fmaf(ao[c2], WO[(size_t)c2*DM + t], a);
  outp[(size_t)b*DM + t] = a;
}

extern "C" void kernel_launch(void* const* d_in, const int* in_sizes, int n_in,
                              void* d_out, int out_size, void* d_ws, size_t ws_size,
                              hipStream_t stream)
{
  (void)in_sizes; (void)n_in; (void)out_size; (void)ws_size;
  const float* x    = (const float*)d_in[0];
  const float* hw   = (const float*)d_in[1];
  const float* embW = (const float*)d_in[2];
  const float* embB = (const float*)d_in[3];
  const float* skW  = (const float*)d_in[4];
  const float* skB  = (const float*)d_in[5];
  const float* inW  = (const float*)d_in[6];
  const float* xpW  = (const float*)d_in[7];
  const float* dtW  = (const float*)d_in[8];
  const float* dtB  = (const float*)d_in[9];
  const float* Alog = (const float*)d_in[10];
  const float* Bb   = (const float*)d_in[11];
  const float* Cb   = (const float*)d_in[12];
  const float* Bnw  = (const float*)d_in[13];
  const float* Cnw  = (const float*)d_in[14];
  const float* rf   = (const float*)d_in[15];
  const float* Dpar = (const float*)d_in[16];
  const float* outW = (const float*)d_in[17];
  const float* lnW  = (const float*)d_in[18];
  const float* lnB  = (const float*)d_in[19];
  const float* fnW  = (const float*)d_in[20];
  const float* fnB  = (const float*)d_in[21];
  const float* WQ = (const float*)d_in[22]; const float* bQ = (const float*)d_in[23];
  const float* WK = (const float*)d_in[24]; const float* bK = (const float*)d_in[25];
  const float* WV = (const float*)d_in[26]; const float* bV = (const float*)d_in[27];
  const float* WO = (const float*)d_in[28]; const float* bO = (const float*)d_in[29];

  float* ws = (float*)d_ws;
  size_t off = 0;
  float* hb    = ws + off; off += (size_t)BSZ*SEQL*DM;
  float* sk    = ws + off; off += (size_t)BSZ*SEQL*DM;
  __half* xph  = (__half*)(ws + off); off += (size_t)BSZ*SEQL*DI/2;
  __half* zsh  = (__half*)(ws + off); off += (size_t)BSZ*SEQL*DI/2;
  float* Bmb   = ws + off; off += (size_t)BSZ*SEQL*DS;
  float* Cmb   = ws + off; off += (size_t)BSZ*SEQL*DS;
  float* lamb  = ws + off; off += (size_t)BSZ*SEQL;
  float* mdtb  = ws + off; off += (size_t)BSZ*SEQL;
  float* dtin  = ws + off; off += (size_t)BSZ*SEQL;
  float* Shalf = ws + off; off += (size_t)BSZ*(SEQL/NROWS)*DI;
  float* hend  = ws + off; off += (size_t)BSZ*NC*DI*DS;
  float2* cst  = (float2*)(ws + off); off += (size_t)BSZ*SEQL*16;
  double* csum_g = (double*)(ws + off); off += (size_t)BSZ*SEQL*2;
  int* idxl_g  = (int*)(ws + off); off += (size_t)BSZ*KLM;
  float* mog   = ws + off; off += (size_t)BSZ*DM;
  float* attnog= ws + off; off += (size_t)BSZ*DM;

  embed_kernel<<<BSZ*SEQL/EROWS, 256, 0, stream>>>(x, hw, embW, embB, skW, skB, hb, sk);

  for (int i=0;i<NL;i++){
    pre_kernel<<<BSZ*SEQL/NROWS, 256, 0, stream>>>(hb,
        inW + (size_t)i*DM*2*DI, xpW + (size_t)i*DI*34,
        dtW + (size_t)i*DI, dtB + (size_t)i*DI,
        Bb + i*DS, Cb + i*DS, Bnw + i*DS, Cnw + i*DS,
        lnW + i*DM, lnB + i*DM,
        xph, zsh, dtin, Shalf, Bmb, Cmb, lamb, mdtb);
    cumsum_kernel<<<BSZ, 256, 0, stream>>>(mdtb, csum_g);
    csfill_kernel<<<BSZ*SEQL/256, 256, 0, stream>>>(csum_g, rf + i*8, cst);
    scan1_kernel<<<BSZ*NC, 512, 0, stream>>>(xph, dtin,
        dtW + (size_t)i*DI, dtB + (size_t)i*DI,
        Bmb, lamb, cst, Alog + (size_t)i*DI*DS, hend);
    scan2_kernel<<<BSZ*DI, 128, 0, stream>>>(hend, Shalf, Alog + (size_t)i*DI*DS);
    scan3post_kernel<<<BSZ*NC, 512, 0, stream>>>(xph, dtin,
        dtW + (size_t)i*DI, dtB + (size_t)i*DI,
        Bmb, Cmb, lamb, zsh, cst,
        Alog + (size_t)i*DI*DS, Dpar + (size_t)i*DI, hend,
        outW + (size_t)i*DI*DM, hb);
  }

  topk_kernel<<<BSZ, 256, 0, stream>>>(hb, hw, fnW, fnB, idxl_g, mog);
  attnmid_kernel<<<BSZ*NHEAD, 256, 0, stream>>>(sk, idxl_g, mog,
      WQ, bQ, WK, bK, WV, bV, attnog);
  attnout_kernel<<<BSZ, 128, 0, stream>>>(attnog, WO, bO, (float*)d_out);
}